// Round 1
// baseline (2339.715 us; speedup 1.0000x reference)
//
#include <hip/hip_runtime.h>
#include <hip/hip_bf16.h>

typedef __attribute__((ext_vector_type(4))) float f32x4;
typedef __attribute__((ext_vector_type(8))) short bf16x8;

#define D 128

__device__ inline short f2bf(float x) {
    __hip_bfloat16 h = __float2bfloat16(x);   // RTNE, compiler can fuse to v_cvt_pk_bf16_f32
    return __builtin_bit_cast(short, h);
}

__device__ inline bf16x8 pack8(f32x4 lo, f32x4 hi) {
    bf16x8 b;
    b[0] = f2bf(lo[0]); b[1] = f2bf(lo[1]); b[2] = f2bf(lo[2]); b[3] = f2bf(lo[3]);
    b[4] = f2bf(hi[0]); b[5] = f2bf(hi[1]); b[6] = f2bf(hi[2]); b[7] = f2bf(hi[3]);
    return b;
}

// One edge per 32-lane group; each lane handles 4 consecutive floats (float4 gather,
// 4x atomicAdd scatter). out[row] += X[col] * val.
__global__ __launch_bounds__(256)
void scatter_edges(const float* __restrict__ X, const int* __restrict__ row,
                   const int* __restrict__ col, const float* __restrict__ val,
                   float* out, int nE)
{
    int t = blockIdx.x * 256 + threadIdx.x;
    int e = t >> 5;
    if (e >= nE) return;
    int l = t & 31;
    int r = row[e];
    int c = col[e];
    float v = val[e];
    f32x4 x = *reinterpret_cast<const f32x4*>(X + (size_t)c * D + l * 4);
    float* o = out + (size_t)r * D + l * 4;
    unsafeAtomicAdd(o + 0, x[0] * v);
    unsafeAtomicAdd(o + 1, x[1] * v);
    unsafeAtomicAdd(o + 2, x[2] * v);
    unsafeAtomicAdd(o + 3, x[3] * v);
}

// out[r][:] = relu(Xself[r] @ Wself^T + neigh[r] @ Wneigh^T), neigh stored IN-PLACE in out.
// View as C[M x 128] = A[M x 256] @ B[256 x 128], A = [Xself | neigh], B^T rows = [Wself | Wneigh].
// 4 waves/block; wave w owns output cols [32w, 32w+32) (two 16-col MFMA tiles) and keeps its
// B fragments (bf16) in registers for all rows the block processes (128 rows/block).
__global__ __launch_bounds__(256)
void gemm_relu_inplace(const float* __restrict__ Xself,
                       const float* __restrict__ Wself,
                       const float* __restrict__ Wneigh,
                       float* out, int nRows)
{
    const int tid  = threadIdx.x;
    const int wave = tid >> 6;
    const int lane = tid & 63;
    const int l15  = lane & 15;
    const int lhi  = lane >> 4;

    // B fragment for (n, kb): lane holds B_t[j][k..k+7] where j = 32*wave + 16n + l15,
    // k = 32*kb + 8*lhi. B_t[j][k] = (k<128 ? Wself[j][k] : Wneigh[j][k-128]).
    bf16x8 bfrag[2][8];
#pragma unroll
    for (int n = 0; n < 2; ++n) {
        int j = wave * 32 + n * 16 + l15;
#pragma unroll
        for (int kb = 0; kb < 8; ++kb) {
            int k = kb * 32 + lhi * 8;
            const float* src = (kb < 4) ? (Wself + j * D + k)
                                        : (Wneigh + j * D + (k - 128));
            f32x4 lo = *reinterpret_cast<const f32x4*>(src);
            f32x4 hi = *reinterpret_cast<const f32x4*>(src + 4);
            bfrag[n][kb] = pack8(lo, hi);
        }
    }

    const int ROWS_PER_BLOCK = 128;
    int r0base = blockIdx.x * ROWS_PER_BLOCK;
#pragma unroll 1
    for (int it = 0; it < 8; ++it) {
        int r0 = r0base + it * 16;
        if (r0 >= nRows) break;

        // A fragments: lane holds A[r0+l15][k..k+7], k = 32*kb + 8*lhi.
        // kb 0..3 -> Xself row, kb 4..7 -> neigh row (currently stored in out).
        const float* xrow = Xself + (size_t)(r0 + l15) * D;
        const float* nrow = out   + (size_t)(r0 + l15) * D;
        bf16x8 afrag[8];
#pragma unroll
        for (int kb = 0; kb < 8; ++kb) {
            const float* src = (kb < 4) ? (xrow + kb * 32 + lhi * 8)
                                        : (nrow + (kb - 4) * 32 + lhi * 8);
            f32x4 lo = *reinterpret_cast<const f32x4*>(src);
            f32x4 hi = *reinterpret_cast<const f32x4*>(src + 4);
            afrag[kb] = pack8(lo, hi);
        }
        // In-place hazard fence: every wave's neigh loads must complete before ANY wave's
        // stores to the same rows. Force load completion, then block barrier.
        asm volatile("s_waitcnt vmcnt(0)" ::: "memory");
        __syncthreads();

        f32x4 acc0 = {0.f, 0.f, 0.f, 0.f};
        f32x4 acc1 = {0.f, 0.f, 0.f, 0.f};
#pragma unroll
        for (int kb = 0; kb < 8; ++kb) {
            acc0 = __builtin_amdgcn_mfma_f32_16x16x32_bf16(afrag[kb], bfrag[0][kb], acc0, 0, 0, 0);
            acc1 = __builtin_amdgcn_mfma_f32_16x16x32_bf16(afrag[kb], bfrag[1][kb], acc1, 0, 0, 0);
        }

        // C/D layout (verified m89/m91): col = lane&15, row = (lane>>4)*4 + reg.
#pragma unroll
        for (int i = 0; i < 4; ++i) {
            int rr = r0 + lhi * 4 + i;
            float v0 = acc0[i]; v0 = v0 > 0.f ? v0 : 0.f;
            float v1 = acc1[i]; v1 = v1 > 0.f ? v1 : 0.f;
            out[(size_t)rr * D + wave * 32 + l15]      = v0;
            out[(size_t)rr * D + wave * 32 + 16 + l15] = v1;
        }
    }
}

extern "C" void kernel_launch(void* const* d_in, const int* in_sizes, int n_in,
                              void* d_out, int out_size, void* d_ws, size_t ws_size,
                              hipStream_t stream)
{
    const float* Xg_self  = (const float*)d_in[0];
    const float* Xs_self  = (const float*)d_in[1];
    const float* Xs_for_g = (const float*)d_in[2];
    const float* Xg_for_s = (const float*)d_in[3];
    const int*   row_gs   = (const int*)d_in[4];
    const int*   col_gs   = (const int*)d_in[5];
    const float* val_gs   = (const float*)d_in[6];
    const int*   row_sg   = (const int*)d_in[7];
    const int*   col_sg   = (const int*)d_in[8];
    const float* val_sg   = (const float*)d_in[9];
    const float* Wg_self  = (const float*)d_in[10];
    const float* Wg_neigh = (const float*)d_in[11];
    const float* Ws_self  = (const float*)d_in[12];
    const float* Ws_neigh = (const float*)d_in[13];

    const int NG = in_sizes[0] / D;
    const int NS = in_sizes[1] / D;
    const int E1 = in_sizes[4];
    const int E2 = in_sizes[7];

    float* out_g = (float*)d_out;
    float* out_s = out_g + (size_t)NG * D;

    // neigh accumulators live in d_out; zero them every call (deterministic).
    hipMemsetAsync(d_out, 0, (size_t)out_size * sizeof(float), stream);

    {
        long long threads = (long long)E1 * 32;
        int grid = (int)((threads + 255) / 256);
        scatter_edges<<<grid, 256, 0, stream>>>(Xs_for_g, row_gs, col_gs, val_gs, out_g, E1);
    }
    {
        long long threads = (long long)E2 * 32;
        int grid = (int)((threads + 255) / 256);
        scatter_edges<<<grid, 256, 0, stream>>>(Xg_for_s, row_sg, col_sg, val_sg, out_s, E2);
    }
    {
        int grid = (NG + 127) / 128;
        gemm_relu_inplace<<<grid, 256, 0, stream>>>(Xg_self, Wg_self, Wg_neigh, out_g, NG);
    }
    {
        int grid = (NS + 127) / 128;
        gemm_relu_inplace<<<grid, 256, 0, stream>>>(Xs_self, Ws_self, Ws_neigh, out_s, NS);
    }
}

// Round 2
// 527.227 us; speedup vs baseline: 4.4378x; 4.4378x over previous
//
#include <hip/hip_runtime.h>
#include <hip/hip_bf16.h>

typedef __attribute__((ext_vector_type(4))) float f32x4;
typedef __attribute__((ext_vector_type(2))) float f32x2;
typedef __attribute__((ext_vector_type(8))) short bf16x8;

#define D 128

__device__ inline short f2bf(float x) {
    __hip_bfloat16 h = __float2bfloat16(x);
    return __builtin_bit_cast(short, h);
}

__device__ inline bf16x8 pack8(f32x4 lo, f32x4 hi) {
    bf16x8 b;
    b[0] = f2bf(lo[0]); b[1] = f2bf(lo[1]); b[2] = f2bf(lo[2]); b[3] = f2bf(lo[3]);
    b[4] = f2bf(hi[0]); b[5] = f2bf(hi[1]); b[6] = f2bf(hi[2]); b[7] = f2bf(hi[3]);
    return b;
}

// ---------------- CSR build ----------------

__global__ __launch_bounds__(256)
void hist_kernel(const int* __restrict__ row, int* __restrict__ cnt, int E)
{
    int e = blockIdx.x * 256 + threadIdx.x;
    if (e < E) atomicAdd(&cnt[row[e]], 1);
}

// Each block scans 1024 counts -> per-element block-local EXCLUSIVE prefix + block total.
__global__ __launch_bounds__(256)
void scan1_kernel(const int* __restrict__ cnt, int* __restrict__ part,
                  int* __restrict__ blksums, int N)
{
    __shared__ int wsum[4];
    int t = threadIdx.x;
    int base = blockIdx.x * 1024 + t * 4;
    int v0 = base + 0 < N ? cnt[base + 0] : 0;
    int v1 = base + 1 < N ? cnt[base + 1] : 0;
    int v2 = base + 2 < N ? cnt[base + 2] : 0;
    int v3 = base + 3 < N ? cnt[base + 3] : 0;
    int s = v0 + v1 + v2 + v3;
    int lane = t & 63, w = t >> 6;
    int x = s;
#pragma unroll
    for (int off = 1; off < 64; off <<= 1) {
        int y = __shfl_up(x, off);
        if (lane >= off) x += y;
    }
    if (lane == 63) wsum[w] = x;
    __syncthreads();
    int woff = 0;
    for (int i = 0; i < w; ++i) woff += wsum[i];
    int incl = x + woff;        // inclusive over thread sums
    int excl = incl - s;
    if (base + 0 < N) part[base + 0] = excl;
    if (base + 1 < N) part[base + 1] = excl + v0;
    if (base + 2 < N) part[base + 2] = excl + v0 + v1;
    if (base + 3 < N) part[base + 3] = excl + v0 + v1 + v2;
    if (t == 255) blksums[blockIdx.x] = incl;
}

__global__ void scan2_kernel(int* blksums, int nb)
{
    if (threadIdx.x == 0 && blockIdx.x == 0) {
        int run = 0;
        for (int i = 0; i < nb; ++i) { int t = blksums[i]; blksums[i] = run; run += t; }
    }
}

__global__ __launch_bounds__(256)
void scan3_kernel(int* __restrict__ start, int* __restrict__ cursor,
                  const int* __restrict__ blksums, int N)
{
    int i = blockIdx.x * 256 + threadIdx.x;
    if (i < N) {
        int v = start[i] + blksums[i >> 10];
        start[i] = v;
        cursor[i] = v;
    }
}

__global__ __launch_bounds__(256)
void fill_kernel(const int* __restrict__ row, const int* __restrict__ col,
                 const float* __restrict__ val, int* __restrict__ cursor,
                 int2* __restrict__ pairs, int E)
{
    int e = blockIdx.x * 256 + threadIdx.x;
    if (e < E) {
        int r = row[e];
        int p = atomicAdd(&cursor[r], 1);
        pairs[p] = make_int2(col[e], __float_as_int(val[e]));
    }
}

// One wave per output row: neigh[r] = sum_{e in row r} X[col_e] * val_e.
// Lane l accumulates floats [2l, 2l+1]; each edge is one coalesced 512B read of X[col].
__global__ __launch_bounds__(256)
void gather_kernel(const float* __restrict__ X, const int* __restrict__ start,
                   const int* __restrict__ cnt, const int2* __restrict__ pairs,
                   float* __restrict__ neigh, int N)
{
    int wid = (blockIdx.x * 256 + threadIdx.x) >> 6;
    if (wid >= N) return;
    int lane = threadIdx.x & 63;
    int s = start[wid];
    int n = cnt[wid];
    f32x2 acc = {0.f, 0.f};
    for (int i = 0; i < n; ++i) {
        int2 p = pairs[s + i];
        float v = __int_as_float(p.y);
        f32x2 x = *reinterpret_cast<const f32x2*>(X + (size_t)p.x * D + lane * 2);
        acc[0] += x[0] * v;
        acc[1] += x[1] * v;
    }
    *reinterpret_cast<f32x2*>(neigh + (size_t)wid * D + lane * 2) = acc;
}

// ---------------- fallback scatter (ws too small) ----------------

__global__ __launch_bounds__(256)
void scatter_edges(const float* __restrict__ X, const int* __restrict__ row,
                   const int* __restrict__ col, const float* __restrict__ val,
                   float* out, int nE)
{
    int t = blockIdx.x * 256 + threadIdx.x;
    int e = t >> 5;
    if (e >= nE) return;
    int l = t & 31;
    int r = row[e];
    int c = col[e];
    float v = val[e];
    f32x4 x = *reinterpret_cast<const f32x4*>(X + (size_t)c * D + l * 4);
    float* o = out + (size_t)r * D + l * 4;
    unsafeAtomicAdd(o + 0, x[0] * v);
    unsafeAtomicAdd(o + 1, x[1] * v);
    unsafeAtomicAdd(o + 2, x[2] * v);
    unsafeAtomicAdd(o + 3, x[3] * v);
}

// ---------------- fused GEMM + relu ----------------
// out[r] = relu([Xself[r] | Neigh[r]] (1x256) @ [Wself;Wneigh]^T).
// FENCE=true when Neigh aliases out (in-place): block-local hazard fence per 16-row tile.
template<bool FENCE>
__global__ __launch_bounds__(256)
void gemm_relu(const float* __restrict__ Xself, const float* __restrict__ Neigh,
               const float* __restrict__ Wself, const float* __restrict__ Wneigh,
               float* __restrict__ out, int nRows)
{
    const int tid  = threadIdx.x;
    const int wave = tid >> 6;
    const int lane = tid & 63;
    const int l15  = lane & 15;
    const int lhi  = lane >> 4;

    bf16x8 bfrag[2][8];
#pragma unroll
    for (int n = 0; n < 2; ++n) {
        int j = wave * 32 + n * 16 + l15;
#pragma unroll
        for (int kb = 0; kb < 8; ++kb) {
            int k = kb * 32 + lhi * 8;
            const float* src = (kb < 4) ? (Wself + j * D + k)
                                        : (Wneigh + j * D + (k - 128));
            f32x4 lo = *reinterpret_cast<const f32x4*>(src);
            f32x4 hi = *reinterpret_cast<const f32x4*>(src + 4);
            bfrag[n][kb] = pack8(lo, hi);
        }
    }

    const int ROWS_PER_BLOCK = 128;
    int r0base = blockIdx.x * ROWS_PER_BLOCK;
#pragma unroll 1
    for (int it = 0; it < 8; ++it) {
        int r0 = r0base + it * 16;
        if (r0 >= nRows) break;

        const float* xrow = Xself + (size_t)(r0 + l15) * D;
        const float* nrow = Neigh + (size_t)(r0 + l15) * D;
        bf16x8 afrag[8];
#pragma unroll
        for (int kb = 0; kb < 8; ++kb) {
            const float* src = (kb < 4) ? (xrow + kb * 32 + lhi * 8)
                                        : (nrow + (kb - 4) * 32 + lhi * 8);
            f32x4 lo = *reinterpret_cast<const f32x4*>(src);
            f32x4 hi = *reinterpret_cast<const f32x4*>(src + 4);
            afrag[kb] = pack8(lo, hi);
        }
        if (FENCE) {
            asm volatile("s_waitcnt vmcnt(0)" ::: "memory");
            __syncthreads();
        }

        f32x4 acc0 = {0.f, 0.f, 0.f, 0.f};
        f32x4 acc1 = {0.f, 0.f, 0.f, 0.f};
#pragma unroll
        for (int kb = 0; kb < 8; ++kb) {
            acc0 = __builtin_amdgcn_mfma_f32_16x16x32_bf16(afrag[kb], bfrag[0][kb], acc0, 0, 0, 0);
            acc1 = __builtin_amdgcn_mfma_f32_16x16x32_bf16(afrag[kb], bfrag[1][kb], acc1, 0, 0, 0);
        }

        // C/D layout: col = lane&15, row = (lane>>4)*4 + reg.
#pragma unroll
        for (int i = 0; i < 4; ++i) {
            int rr = r0 + lhi * 4 + i;
            float v0 = acc0[i]; v0 = v0 > 0.f ? v0 : 0.f;
            float v1 = acc1[i]; v1 = v1 > 0.f ? v1 : 0.f;
            out[(size_t)rr * D + wave * 32 + l15]      = v0;
            out[(size_t)rr * D + wave * 32 + 16 + l15] = v1;
        }
    }
}

// ---------------- launch ----------------

extern "C" void kernel_launch(void* const* d_in, const int* in_sizes, int n_in,
                              void* d_out, int out_size, void* d_ws, size_t ws_size,
                              hipStream_t stream)
{
    const float* Xg_self  = (const float*)d_in[0];
    const float* Xs_self  = (const float*)d_in[1];
    const float* Xs_for_g = (const float*)d_in[2];
    const float* Xg_for_s = (const float*)d_in[3];
    const int*   row_gs   = (const int*)d_in[4];
    const int*   col_gs   = (const int*)d_in[5];
    const float* val_gs   = (const float*)d_in[6];
    const int*   row_sg   = (const int*)d_in[7];
    const int*   col_sg   = (const int*)d_in[8];
    const float* val_sg   = (const float*)d_in[9];
    const float* Wg_self  = (const float*)d_in[10];
    const float* Wg_neigh = (const float*)d_in[11];
    const float* Ws_self  = (const float*)d_in[12];
    const float* Ws_neigh = (const float*)d_in[13];

    const int NG = in_sizes[0] / D;
    const int NS = in_sizes[1] / D;
    const int E1 = in_sizes[4];
    const int E2 = in_sizes[7];

    float* out_g = (float*)d_out;
    float* out_s = out_g + (size_t)NG * D;

    // ---- workspace layout ----
    size_t off = 0;
    auto alloc = [&](size_t bytes) -> size_t {
        off = (off + 255) & ~(size_t)255;
        size_t o = off;
        off += bytes;
        return o;
    };
    // direction 0 (gs): N=NG, E=E1 ; direction 1 (sg): N=NS, E=E2
    size_t cnt0_o    = alloc(sizeof(int) * NG);
    size_t start0_o  = alloc(sizeof(int) * NG);
    size_t cursor0_o = alloc(sizeof(int) * NG);
    size_t pairs0_o  = alloc(sizeof(int2) * (size_t)E1);
    size_t blk0_o    = alloc(sizeof(int) * 256);
    size_t cnt1_o    = alloc(sizeof(int) * NS);
    size_t start1_o  = alloc(sizeof(int) * NS);
    size_t cursor1_o = alloc(sizeof(int) * NS);
    size_t pairs1_o  = alloc(sizeof(int2) * (size_t)E2);
    size_t blk1_o    = alloc(sizeof(int) * 256);
    size_t csr_bytes = off;
    size_t neigh0_o  = alloc(sizeof(float) * (size_t)NG * D);
    size_t neigh1_o  = alloc(sizeof(float) * (size_t)NS * D);
    size_t full_bytes = off;

    char* ws = (char*)d_ws;

    bool have_csr   = ws_size >= csr_bytes;
    bool have_neigh = ws_size >= full_bytes;

    if (!have_csr) {
        // ---- fallback: R1 atomic scatter path ----
        hipMemsetAsync(d_out, 0, (size_t)out_size * sizeof(float), stream);
        {
            long long threads = (long long)E1 * 32;
            int grid = (int)((threads + 255) / 256);
            scatter_edges<<<grid, 256, 0, stream>>>(Xs_for_g, row_gs, col_gs, val_gs, out_g, E1);
        }
        {
            long long threads = (long long)E2 * 32;
            int grid = (int)((threads + 255) / 256);
            scatter_edges<<<grid, 256, 0, stream>>>(Xg_for_s, row_sg, col_sg, val_sg, out_s, E2);
        }
        gemm_relu<true><<<(NG + 127) / 128, 256, 0, stream>>>(Xg_self, out_g, Wg_self, Wg_neigh, out_g, NG);
        gemm_relu<true><<<(NS + 127) / 128, 256, 0, stream>>>(Xs_self, out_s, Ws_self, Ws_neigh, out_s, NS);
        return;
    }

    float* neigh0 = have_neigh ? (float*)(ws + neigh0_o) : out_g;
    float* neigh1 = have_neigh ? (float*)(ws + neigh1_o) : out_s;

    struct Dir {
        int N, E;
        const int *row, *col;
        const float *val, *X;
        int *cnt, *start, *cursor, *blk;
        int2* pairs;
        float* neigh;
    } dirs[2] = {
        { NG, E1, row_gs, col_gs, val_gs, Xs_for_g,
          (int*)(ws + cnt0_o), (int*)(ws + start0_o), (int*)(ws + cursor0_o),
          (int*)(ws + blk0_o), (int2*)(ws + pairs0_o), neigh0 },
        { NS, E2, row_sg, col_sg, val_sg, Xg_for_s,
          (int*)(ws + cnt1_o), (int*)(ws + start1_o), (int*)(ws + cursor1_o),
          (int*)(ws + blk1_o), (int2*)(ws + pairs1_o), neigh1 },
    };

    for (int d = 0; d < 2; ++d) {
        Dir& dd = dirs[d];
        hipMemsetAsync(dd.cnt, 0, sizeof(int) * dd.N, stream);
        hist_kernel<<<(dd.E + 255) / 256, 256, 0, stream>>>(dd.row, dd.cnt, dd.E);
        int nb = (dd.N + 1023) / 1024;
        scan1_kernel<<<nb, 256, 0, stream>>>(dd.cnt, dd.start, dd.blk, dd.N);
        scan2_kernel<<<1, 64, 0, stream>>>(dd.blk, nb);
        scan3_kernel<<<(dd.N + 255) / 256, 256, 0, stream>>>(dd.start, dd.cursor, dd.blk, dd.N);
        fill_kernel<<<(dd.E + 255) / 256, 256, 0, stream>>>(dd.row, dd.col, dd.val, dd.cursor, dd.pairs, dd.E);
        gather_kernel<<<(dd.N * 64 + 255) / 256, 256, 0, stream>>>(dd.X, dd.start, dd.cnt, dd.pairs, dd.neigh, dd.N);
    }

    if (have_neigh) {
        gemm_relu<false><<<(NG + 127) / 128, 256, 0, stream>>>(Xg_self, neigh0, Wg_self, Wg_neigh, out_g, NG);
        gemm_relu<false><<<(NS + 127) / 128, 256, 0, stream>>>(Xs_self, neigh1, Ws_self, Ws_neigh, out_s, NS);
    } else {
        gemm_relu<true><<<(NG + 127) / 128, 256, 0, stream>>>(Xg_self, out_g, Wg_self, Wg_neigh, out_g, NG);
        gemm_relu<true><<<(NS + 127) / 128, 256, 0, stream>>>(Xs_self, out_s, Ws_self, Ws_neigh, out_s, NS);
    }
}

// Round 3
// 454.422 us; speedup vs baseline: 5.1488x; 1.1602x over previous
//
#include <hip/hip_runtime.h>
#include <hip/hip_bf16.h>

typedef __attribute__((ext_vector_type(4))) float f32x4;
typedef __attribute__((ext_vector_type(2))) float f32x2;
typedef __attribute__((ext_vector_type(8))) short bf16x8;

#define D 128

__device__ inline short f2bf(float x) {
    __hip_bfloat16 h = __float2bfloat16(x);
    return __builtin_bit_cast(short, h);
}

__device__ inline bf16x8 pack8(f32x4 lo, f32x4 hi) {
    bf16x8 b;
    b[0] = f2bf(lo[0]); b[1] = f2bf(lo[1]); b[2] = f2bf(lo[2]); b[3] = f2bf(lo[3]);
    b[4] = f2bf(hi[0]); b[5] = f2bf(hi[1]); b[6] = f2bf(hi[2]); b[7] = f2bf(hi[3]);
    return b;
}

// ---------------- CSR build (both directions share one index space [0, NG+NS)) ----

__global__ __launch_bounds__(256)
void hist2_kernel(const int* __restrict__ rowA, int EA,
                  const int* __restrict__ rowB, int NGoff,
                  int* __restrict__ cnt, int Etot)
{
    int e = blockIdx.x * 256 + threadIdx.x;
    if (e >= Etot) return;
    int r = (e < EA) ? rowA[e] : (rowB[e - EA] + NGoff);
    atomicAdd(&cnt[r], 1);
}

// Block scans 1024 counts -> exclusive prefix + block total.
__global__ __launch_bounds__(256)
void scan1_kernel(const int* __restrict__ cnt, int* __restrict__ part,
                  int* __restrict__ blksums, int N)
{
    __shared__ int wsum[4];
    int t = threadIdx.x;
    int base = blockIdx.x * 1024 + t * 4;
    int v0 = base + 0 < N ? cnt[base + 0] : 0;
    int v1 = base + 1 < N ? cnt[base + 1] : 0;
    int v2 = base + 2 < N ? cnt[base + 2] : 0;
    int v3 = base + 3 < N ? cnt[base + 3] : 0;
    int s = v0 + v1 + v2 + v3;
    int lane = t & 63, w = t >> 6;
    int x = s;
#pragma unroll
    for (int off = 1; off < 64; off <<= 1) {
        int y = __shfl_up(x, off);
        if (lane >= off) x += y;
    }
    if (lane == 63) wsum[w] = x;
    __syncthreads();
    int woff = 0;
    for (int i = 0; i < w; ++i) woff += wsum[i];
    int incl = x + woff;
    int excl = incl - s;
    if (base + 0 < N) part[base + 0] = excl;
    if (base + 1 < N) part[base + 1] = excl + v0;
    if (base + 2 < N) part[base + 2] = excl + v0 + v1;
    if (base + 3 < N) part[base + 3] = excl + v0 + v1 + v2;
    if (t == 255) blksums[blockIdx.x] = incl;
}

// Exclusive scan of up to 1024 block sums with one 256-thread block (4 vals/thread not
// needed: nb <= 256 here).
__global__ __launch_bounds__(256)
void scan2_kernel(int* __restrict__ blksums, int nb)
{
    __shared__ int wsum[4];
    int t = threadIdx.x;
    int v = t < nb ? blksums[t] : 0;
    int lane = t & 63, w = t >> 6;
    int x = v;
#pragma unroll
    for (int off = 1; off < 64; off <<= 1) {
        int y = __shfl_up(x, off);
        if (lane >= off) x += y;
    }
    if (lane == 63) wsum[w] = x;
    __syncthreads();
    int woff = 0;
    for (int i = 0; i < w; ++i) woff += wsum[i];
    int excl = x + woff - v;
    if (t < nb) blksums[t] = excl;
}

__global__ __launch_bounds__(256)
void scan3_kernel(int* __restrict__ start, int* __restrict__ cursor,
                  const int* __restrict__ blksums, int N)
{
    int i = blockIdx.x * 256 + threadIdx.x;
    if (i < N) {
        int v = start[i] + blksums[i >> 10];
        start[i] = v;
        cursor[i] = v;
    }
}

__global__ __launch_bounds__(256)
void fill2_kernel(const int* __restrict__ rowA, const int* __restrict__ colA,
                  const float* __restrict__ valA, int EA,
                  const int* __restrict__ rowB, const int* __restrict__ colB,
                  const float* __restrict__ valB, int NGoff,
                  int* __restrict__ cursor, int2* __restrict__ pairs, int Etot)
{
    int e = blockIdx.x * 256 + threadIdx.x;
    if (e >= Etot) return;
    int r, c; float v;
    if (e < EA) { r = rowA[e]; c = colA[e]; v = valA[e]; }
    else { int e2 = e - EA; r = rowB[e2] + NGoff; c = colB[e2]; v = valB[e2]; }
    int p = atomicAdd(&cursor[r], 1);
    pairs[p] = make_int2(c, __float_as_int(v));
}

// One wave per output row; rows [0,NG) gather from X0 -> neigh0, rows [NG,N) from X1 -> neigh1.
// Edge loop unrolled x4 so 4 independent 512B row-reads are in flight.
__global__ __launch_bounds__(256)
void gather_kernel(const float* __restrict__ X0, const float* __restrict__ X1,
                   const int* __restrict__ start, const int* __restrict__ cnt,
                   const int2* __restrict__ pairs,
                   float* __restrict__ neigh0, float* __restrict__ neigh1,
                   int NG, int N)
{
    int wid = (blockIdx.x * 256 + threadIdx.x) >> 6;
    if (wid >= N) return;
    int lane = threadIdx.x & 63;
    const float* X = (wid < NG) ? X0 : X1;
    float* dst = (wid < NG) ? (neigh0 + (size_t)wid * D)
                            : (neigh1 + (size_t)(wid - NG) * D);
    int s = __builtin_amdgcn_readfirstlane(start[wid]);
    int n = __builtin_amdgcn_readfirstlane(cnt[wid]);
    f32x2 acc = {0.f, 0.f};
    int i = 0;
    for (; i + 4 <= n; i += 4) {
        int2 p0 = pairs[s + i + 0];
        int2 p1 = pairs[s + i + 1];
        int2 p2 = pairs[s + i + 2];
        int2 p3 = pairs[s + i + 3];
        f32x2 x0 = *reinterpret_cast<const f32x2*>(X + (size_t)p0.x * D + lane * 2);
        f32x2 x1 = *reinterpret_cast<const f32x2*>(X + (size_t)p1.x * D + lane * 2);
        f32x2 x2 = *reinterpret_cast<const f32x2*>(X + (size_t)p2.x * D + lane * 2);
        f32x2 x3 = *reinterpret_cast<const f32x2*>(X + (size_t)p3.x * D + lane * 2);
        float v0 = __int_as_float(p0.y), v1 = __int_as_float(p1.y);
        float v2 = __int_as_float(p2.y), v3 = __int_as_float(p3.y);
        acc[0] += x0[0] * v0; acc[1] += x0[1] * v0;
        acc[0] += x1[0] * v1; acc[1] += x1[1] * v1;
        acc[0] += x2[0] * v2; acc[1] += x2[1] * v2;
        acc[0] += x3[0] * v3; acc[1] += x3[1] * v3;
    }
    for (; i < n; ++i) {
        int2 p = pairs[s + i];
        float v = __int_as_float(p.y);
        f32x2 x = *reinterpret_cast<const f32x2*>(X + (size_t)p.x * D + lane * 2);
        acc[0] += x[0] * v;
        acc[1] += x[1] * v;
    }
    *reinterpret_cast<f32x2*>(dst + lane * 2) = acc;
}

// ---------------- fallback scatter (ws too small) ----------------

__global__ __launch_bounds__(256)
void scatter_edges(const float* __restrict__ X, const int* __restrict__ row,
                   const int* __restrict__ col, const float* __restrict__ val,
                   float* out, int nE)
{
    int t = blockIdx.x * 256 + threadIdx.x;
    int e = t >> 5;
    if (e >= nE) return;
    int l = t & 31;
    int r = row[e];
    int c = col[e];
    float v = val[e];
    f32x4 x = *reinterpret_cast<const f32x4*>(X + (size_t)c * D + l * 4);
    float* o = out + (size_t)r * D + l * 4;
    unsafeAtomicAdd(o + 0, x[0] * v);
    unsafeAtomicAdd(o + 1, x[1] * v);
    unsafeAtomicAdd(o + 2, x[2] * v);
    unsafeAtomicAdd(o + 3, x[3] * v);
}

// ---------------- fused GEMM + relu, both directions in one launch ------------
// out[r] = relu([Xself[r] | Neigh[r]] (1x256) @ [Wself;Wneigh]^T).
// 32 rows per block (2 MFMA row-tiles); 4 waves split the 128 output cols.
// FENCE=true when Neigh aliases out (fallback in-place path).
template<bool FENCE>
__global__ __launch_bounds__(256)
void gemm_relu(const float* __restrict__ Xself0, const float* __restrict__ Neigh0,
               const float* __restrict__ Wself0, const float* __restrict__ Wneigh0,
               float* __restrict__ out0, int n0,
               const float* __restrict__ Xself1, const float* __restrict__ Neigh1,
               const float* __restrict__ Wself1, const float* __restrict__ Wneigh1,
               float* __restrict__ out1, int n1)
{
    const int ROWS_PER_BLOCK = 32;
    int blocks0 = (n0 + ROWS_PER_BLOCK - 1) / ROWS_PER_BLOCK;

    const float *Xself, *Neigh, *Wself, *Wneigh;
    float* out;
    int nRows, r0base;
    if ((int)blockIdx.x < blocks0) {
        Xself = Xself0; Neigh = Neigh0; Wself = Wself0; Wneigh = Wneigh0;
        out = out0; nRows = n0; r0base = blockIdx.x * ROWS_PER_BLOCK;
    } else {
        Xself = Xself1; Neigh = Neigh1; Wself = Wself1; Wneigh = Wneigh1;
        out = out1; nRows = n1; r0base = (blockIdx.x - blocks0) * ROWS_PER_BLOCK;
    }

    const int tid  = threadIdx.x;
    const int wave = tid >> 6;
    const int lane = tid & 63;
    const int l15  = lane & 15;
    const int lhi  = lane >> 4;

    // B fragment (n, kb): lane holds B_t[j][k..k+7], j = 32*wave + 16n + l15, k = 32*kb + 8*lhi.
    bf16x8 bfrag[2][8];
#pragma unroll
    for (int n = 0; n < 2; ++n) {
        int j = wave * 32 + n * 16 + l15;
#pragma unroll
        for (int kb = 0; kb < 8; ++kb) {
            int k = kb * 32 + lhi * 8;
            const float* src = (kb < 4) ? (Wself + j * D + k)
                                        : (Wneigh + j * D + (k - 128));
            f32x4 lo = *reinterpret_cast<const f32x4*>(src);
            f32x4 hi = *reinterpret_cast<const f32x4*>(src + 4);
            bfrag[n][kb] = pack8(lo, hi);
        }
    }

#pragma unroll
    for (int it = 0; it < ROWS_PER_BLOCK / 16; ++it) {
        int r0 = r0base + it * 16;
        if (r0 >= nRows) break;

        const float* xrow = Xself + (size_t)(r0 + l15) * D;
        const float* nrow = Neigh + (size_t)(r0 + l15) * D;
        bf16x8 afrag[8];
#pragma unroll
        for (int kb = 0; kb < 8; ++kb) {
            const float* src = (kb < 4) ? (xrow + kb * 32 + lhi * 8)
                                        : (nrow + (kb - 4) * 32 + lhi * 8);
            f32x4 lo = *reinterpret_cast<const f32x4*>(src);
            f32x4 hi = *reinterpret_cast<const f32x4*>(src + 4);
            afrag[kb] = pack8(lo, hi);
        }
        if (FENCE) {
            asm volatile("s_waitcnt vmcnt(0)" ::: "memory");
            __syncthreads();
        }

        f32x4 acc0 = {0.f, 0.f, 0.f, 0.f};
        f32x4 acc1 = {0.f, 0.f, 0.f, 0.f};
#pragma unroll
        for (int kb = 0; kb < 8; ++kb) {
            acc0 = __builtin_amdgcn_mfma_f32_16x16x32_bf16(afrag[kb], bfrag[0][kb], acc0, 0, 0, 0);
            acc1 = __builtin_amdgcn_mfma_f32_16x16x32_bf16(afrag[kb], bfrag[1][kb], acc1, 0, 0, 0);
        }

        // C/D layout: col = lane&15, row = (lane>>4)*4 + reg.
#pragma unroll
        for (int i = 0; i < 4; ++i) {
            int rr = r0 + lhi * 4 + i;
            float v0 = acc0[i]; v0 = v0 > 0.f ? v0 : 0.f;
            float v1 = acc1[i]; v1 = v1 > 0.f ? v1 : 0.f;
            out[(size_t)rr * D + wave * 32 + l15]      = v0;
            out[(size_t)rr * D + wave * 32 + 16 + l15] = v1;
        }
    }
}

// ---------------- launch ----------------

extern "C" void kernel_launch(void* const* d_in, const int* in_sizes, int n_in,
                              void* d_out, int out_size, void* d_ws, size_t ws_size,
                              hipStream_t stream)
{
    const float* Xg_self  = (const float*)d_in[0];
    const float* Xs_self  = (const float*)d_in[1];
    const float* Xs_for_g = (const float*)d_in[2];
    const float* Xg_for_s = (const float*)d_in[3];
    const int*   row_gs   = (const int*)d_in[4];
    const int*   col_gs   = (const int*)d_in[5];
    const float* val_gs   = (const float*)d_in[6];
    const int*   row_sg   = (const int*)d_in[7];
    const int*   col_sg   = (const int*)d_in[8];
    const float* val_sg   = (const float*)d_in[9];
    const float* Wg_self  = (const float*)d_in[10];
    const float* Wg_neigh = (const float*)d_in[11];
    const float* Ws_self  = (const float*)d_in[12];
    const float* Ws_neigh = (const float*)d_in[13];

    const int NG = in_sizes[0] / D;
    const int NS = in_sizes[1] / D;
    const int E1 = in_sizes[4];
    const int E2 = in_sizes[7];
    const int N  = NG + NS;
    const int Etot = E1 + E2;

    float* out_g = (float*)d_out;
    float* out_s = out_g + (size_t)NG * D;

    // ---- workspace layout ----
    size_t off = 0;
    auto alloc = [&](size_t bytes) -> size_t {
        off = (off + 255) & ~(size_t)255;
        size_t o = off;
        off += bytes;
        return o;
    };
    size_t cnt_o    = alloc(sizeof(int) * N);
    size_t start_o  = alloc(sizeof(int) * N);
    size_t cursor_o = alloc(sizeof(int) * N);
    size_t pairs_o  = alloc(sizeof(int2) * (size_t)Etot);
    size_t blk_o    = alloc(sizeof(int) * 1024);
    size_t csr_bytes = off;
    size_t neigh0_o  = alloc(sizeof(float) * (size_t)NG * D);
    size_t neigh1_o  = alloc(sizeof(float) * (size_t)NS * D);
    size_t full_bytes = off;

    char* ws = (char*)d_ws;
    bool have_csr   = ws_size >= csr_bytes;
    bool have_neigh = ws_size >= full_bytes;

    if (!have_csr) {
        // ---- fallback: atomic scatter path ----
        hipMemsetAsync(d_out, 0, (size_t)out_size * sizeof(float), stream);
        {
            long long threads = (long long)E1 * 32;
            scatter_edges<<<(int)((threads + 255) / 256), 256, 0, stream>>>(
                Xs_for_g, row_gs, col_gs, val_gs, out_g, E1);
        }
        {
            long long threads = (long long)E2 * 32;
            scatter_edges<<<(int)((threads + 255) / 256), 256, 0, stream>>>(
                Xg_for_s, row_sg, col_sg, val_sg, out_s, E2);
        }
        int blocks0 = (NG + 31) / 32, blocks1 = (NS + 31) / 32;
        gemm_relu<true><<<blocks0 + blocks1, 256, 0, stream>>>(
            Xg_self, out_g, Wg_self, Wg_neigh, out_g, NG,
            Xs_self, out_s, Ws_self, Ws_neigh, out_s, NS);
        return;
    }

    int* cnt    = (int*)(ws + cnt_o);
    int* start  = (int*)(ws + start_o);
    int* cursor = (int*)(ws + cursor_o);
    int2* pairs = (int2*)(ws + pairs_o);
    int* blk    = (int*)(ws + blk_o);
    float* neigh0 = have_neigh ? (float*)(ws + neigh0_o) : out_g;
    float* neigh1 = have_neigh ? (float*)(ws + neigh1_o) : out_s;

    hipMemsetAsync(cnt, 0, sizeof(int) * N, stream);
    hist2_kernel<<<(Etot + 255) / 256, 256, 0, stream>>>(row_gs, E1, row_sg, NG, cnt, Etot);
    int nb = (N + 1023) / 1024;   // 196 for N=200k; scan2 handles nb<=256
    scan1_kernel<<<nb, 256, 0, stream>>>(cnt, start, blk, N);
    scan2_kernel<<<1, 256, 0, stream>>>(blk, nb);
    scan3_kernel<<<(N + 255) / 256, 256, 0, stream>>>(start, cursor, blk, N);
    fill2_kernel<<<(Etot + 255) / 256, 256, 0, stream>>>(
        row_gs, col_gs, val_gs, E1, row_sg, col_sg, val_sg, NG, cursor, pairs, Etot);
    gather_kernel<<<(N * 64 + 255) / 256, 256, 0, stream>>>(
        Xs_for_g, Xg_for_s, start, cnt, pairs, neigh0, neigh1, NG, N);

    int blocks0 = (NG + 31) / 32, blocks1 = (NS + 31) / 32;
    if (have_neigh) {
        gemm_relu<false><<<blocks0 + blocks1, 256, 0, stream>>>(
            Xg_self, neigh0, Wg_self, Wg_neigh, out_g, NG,
            Xs_self, neigh1, Ws_self, Ws_neigh, out_s, NS);
    } else {
        gemm_relu<true><<<blocks0 + blocks1, 256, 0, stream>>>(
            Xg_self, out_g, Wg_self, Wg_neigh, out_g, NG,
            Xs_self, out_s, Ws_self, Ws_neigh, out_s, NS);
    }
}

// Round 4
// 356.266 us; speedup vs baseline: 6.5673x; 1.2755x over previous
//
#include <hip/hip_runtime.h>
#include <hip/hip_bf16.h>
#include <stdint.h>

typedef __attribute__((ext_vector_type(4))) float f32x4;
typedef __attribute__((ext_vector_type(2))) float f32x2;
typedef __attribute__((ext_vector_type(8))) short bf16x8;

#define D 128
#define GLOBAL_AS __attribute__((address_space(1)))
#define LDS_AS __attribute__((address_space(3)))

__device__ inline short f2bf(float x) {
    __hip_bfloat16 h = __float2bfloat16(x);
    return __builtin_bit_cast(short, h);
}

__device__ inline bf16x8 pack8(f32x4 lo, f32x4 hi) {
    bf16x8 b;
    b[0] = f2bf(lo[0]); b[1] = f2bf(lo[1]); b[2] = f2bf(lo[2]); b[3] = f2bf(lo[3]);
    b[4] = f2bf(hi[0]); b[5] = f2bf(hi[1]); b[6] = f2bf(hi[2]); b[7] = f2bf(hi[3]);
    return b;
}

// ---------------- weight pre-pack: Wcat[dir][j][k] bf16, k<128 = Wself, else Wneigh ----

__global__ __launch_bounds__(256)
void wprep_kernel(const float* __restrict__ Wg_self, const float* __restrict__ Wg_neigh,
                  const float* __restrict__ Ws_self, const float* __restrict__ Ws_neigh,
                  short* __restrict__ Wcat)
{
    int t = blockIdx.x * 256 + threadIdx.x;      // 8192 threads, 8 k's each
    if (t >= 2 * 128 * 32) return;
    int dir = t >> 12;
    int rem = t & 4095;
    int j = rem >> 5;
    int k = (rem & 31) * 8;
    const float* Wself  = dir ? Ws_self  : Wg_self;
    const float* Wneigh = dir ? Ws_neigh : Wg_neigh;
    const float* src = (k < 128) ? (Wself + j * D + k) : (Wneigh + j * D + (k - 128));
    f32x4 lo = *reinterpret_cast<const f32x4*>(src);
    f32x4 hi = *reinterpret_cast<const f32x4*>(src + 4);
    *reinterpret_cast<bf16x8*>(Wcat + (size_t)dir * 32768 + j * 256 + k) = pack8(lo, hi);
}

// ---------------- CSR build (both directions share one index space [0, NG+NS)) ----

__global__ __launch_bounds__(256)
void hist2_kernel(const int* __restrict__ rowA, int EA,
                  const int* __restrict__ rowB, int NGoff,
                  int* __restrict__ cnt, int Etot)
{
    int e = blockIdx.x * 256 + threadIdx.x;
    if (e >= Etot) return;
    int r = (e < EA) ? rowA[e] : (rowB[e - EA] + NGoff);
    atomicAdd(&cnt[r], 1);
}

__global__ __launch_bounds__(256)
void scan1_kernel(const int* __restrict__ cnt, int* __restrict__ part,
                  int* __restrict__ blksums, int N)
{
    __shared__ int wsum[4];
    int t = threadIdx.x;
    int base = blockIdx.x * 1024 + t * 4;
    int v0 = base + 0 < N ? cnt[base + 0] : 0;
    int v1 = base + 1 < N ? cnt[base + 1] : 0;
    int v2 = base + 2 < N ? cnt[base + 2] : 0;
    int v3 = base + 3 < N ? cnt[base + 3] : 0;
    int s = v0 + v1 + v2 + v3;
    int lane = t & 63, w = t >> 6;
    int x = s;
#pragma unroll
    for (int off = 1; off < 64; off <<= 1) {
        int y = __shfl_up(x, off);
        if (lane >= off) x += y;
    }
    if (lane == 63) wsum[w] = x;
    __syncthreads();
    int woff = 0;
    for (int i = 0; i < w; ++i) woff += wsum[i];
    int incl = x + woff;
    int excl = incl - s;
    if (base + 0 < N) part[base + 0] = excl;
    if (base + 1 < N) part[base + 1] = excl + v0;
    if (base + 2 < N) part[base + 2] = excl + v0 + v1;
    if (base + 3 < N) part[base + 3] = excl + v0 + v1 + v2;
    if (t == 255) blksums[blockIdx.x] = incl;
}

__global__ __launch_bounds__(256)
void scan2_kernel(int* __restrict__ blksums, int nb)
{
    __shared__ int wsum[4];
    int t = threadIdx.x;
    int v = t < nb ? blksums[t] : 0;
    int lane = t & 63, w = t >> 6;
    int x = v;
#pragma unroll
    for (int off = 1; off < 64; off <<= 1) {
        int y = __shfl_up(x, off);
        if (lane >= off) x += y;
    }
    if (lane == 63) wsum[w] = x;
    __syncthreads();
    int woff = 0;
    for (int i = 0; i < w; ++i) woff += wsum[i];
    int excl = x + woff - v;
    if (t < nb) blksums[t] = excl;
}

__global__ __launch_bounds__(256)
void scan3_kernel(int* __restrict__ start, int* __restrict__ cursor,
                  const int* __restrict__ blksums, int N)
{
    int i = blockIdx.x * 256 + threadIdx.x;
    if (i < N) {
        int v = start[i] + blksums[i >> 10];
        start[i] = v;
        cursor[i] = v;
    }
}

__global__ __launch_bounds__(256)
void fill2_kernel(const int* __restrict__ rowA, const int* __restrict__ colA,
                  const float* __restrict__ valA, int EA,
                  const int* __restrict__ rowB, const int* __restrict__ colB,
                  const float* __restrict__ valB, int NGoff,
                  int* __restrict__ cursor, int2* __restrict__ pairs, int Etot)
{
    int e = blockIdx.x * 256 + threadIdx.x;
    if (e >= Etot) return;
    int r, c; float v;
    if (e < EA) { r = rowA[e]; c = colA[e]; v = valA[e]; }
    else { int e2 = e - EA; r = rowB[e2] + NGoff; c = colB[e2]; v = valB[e2]; }
    int p = atomicAdd(&cursor[r], 1);
    pairs[p] = make_int2(c, __float_as_int(v));
}

// One wave per output row; unroll x8 keeps 8 independent 512B row-reads in flight.
__global__ __launch_bounds__(256)
void gather_kernel(const float* __restrict__ X0, const float* __restrict__ X1,
                   const int* __restrict__ start, const int* __restrict__ cnt,
                   const int2* __restrict__ pairs,
                   float* __restrict__ neigh0, float* __restrict__ neigh1,
                   int NG, int N)
{
    int wid = (blockIdx.x * 256 + threadIdx.x) >> 6;
    if (wid >= N) return;
    int lane = threadIdx.x & 63;
    const float* X = (wid < NG) ? X0 : X1;
    float* dst = (wid < NG) ? (neigh0 + (size_t)wid * D)
                            : (neigh1 + (size_t)(wid - NG) * D);
    int s = __builtin_amdgcn_readfirstlane(start[wid]);
    int n = __builtin_amdgcn_readfirstlane(cnt[wid]);
    f32x2 acc = {0.f, 0.f};
    int i = 0;
    for (; i + 8 <= n; i += 8) {
        f32x2 x[8]; float v[8];
#pragma unroll
        for (int u = 0; u < 8; ++u) {
            int2 p = pairs[s + i + u];
            v[u] = __int_as_float(p.y);
            x[u] = *reinterpret_cast<const f32x2*>(X + (size_t)p.x * D + lane * 2);
        }
#pragma unroll
        for (int u = 0; u < 8; ++u) {
            acc[0] += x[u][0] * v[u];
            acc[1] += x[u][1] * v[u];
        }
    }
    for (; i < n; ++i) {
        int2 p = pairs[s + i];
        float v = __int_as_float(p.y);
        f32x2 x = *reinterpret_cast<const f32x2*>(X + (size_t)p.x * D + lane * 2);
        acc[0] += x[0] * v;
        acc[1] += x[1] * v;
    }
    *reinterpret_cast<f32x2*>(dst + lane * 2) = acc;
}

// ---------------- main GEMM: LDS-staged A, pre-packed bf16 weights ----------------
// Block = 256 thr / 4 waves, 32 rows. LDS row r (1KB) = [Xself[R] | Neigh[R]] f32,
// 16B-chunk-XOR-swizzled (chunk ^ (r&7)) applied on the GLOBAL source side so
// global_load_lds stays linear (rule #21). In-place Neigh==out is safe: all reads
// of a block's rows complete (vmcnt(0)+barrier) before its stores.
__global__ __launch_bounds__(256)
void gemm_relu_main(const float* __restrict__ Xself0, const float* __restrict__ Neigh0,
                    float* __restrict__ out0, int n0,
                    const float* __restrict__ Xself1, const float* __restrict__ Neigh1,
                    float* __restrict__ out1, int n1,
                    const short* __restrict__ Wcat)
{
    __shared__ float A[32 * 256];   // 32 KiB
    const int ROWS = 32;
    int blocks0 = (n0 + ROWS - 1) / ROWS;

    const float *Xself, *Neigh; float* out; int nRows, r0base; const short* Wb;
    if ((int)blockIdx.x < blocks0) {
        Xself = Xself0; Neigh = Neigh0; out = out0; nRows = n0;
        r0base = blockIdx.x * ROWS; Wb = Wcat;
    } else {
        Xself = Xself1; Neigh = Neigh1; out = out1; nRows = n1;
        r0base = ((int)blockIdx.x - blocks0) * ROWS; Wb = Wcat + 32768;
    }

    const int tid = threadIdx.x, wave = tid >> 6, lane = tid & 63;
    const int l15 = lane & 15, lhi = lane >> 4;

    // Stage 32 combined rows. One instruction per row per wave: lanes 0-31 bring the
    // Xself half, lanes 32-63 the Neigh half; per-lane global chunk = (lane&31)^(r&7).
#pragma unroll
    for (int i = 0; i < 8; ++i) {
        int r = wave * 8 + i;
        int R = r0base + r; if (R > nRows - 1) R = nRows - 1;
        const float* half = (lane < 32) ? (Xself + (size_t)R * D) : (Neigh + (size_t)R * D);
        const float* g = half + (((lane & 31) ^ (r & 7)) << 2);
        __builtin_amdgcn_global_load_lds((const GLOBAL_AS uint32_t*)g,
                                         (LDS_AS uint32_t*)(&A[r * 256]), 16, 0, 0);
    }

    // Pre-packed weight fragments: 16 direct 16B loads (L2-resident).
    bf16x8 bfrag[2][8];
#pragma unroll
    for (int n = 0; n < 2; ++n) {
        int j = wave * 32 + n * 16 + l15;
#pragma unroll
        for (int kb = 0; kb < 8; ++kb)
            bfrag[n][kb] = *reinterpret_cast<const bf16x8*>(
                Wb + (size_t)j * 256 + kb * 32 + lhi * 8);
    }

    asm volatile("s_waitcnt vmcnt(0)" ::: "memory");
    __syncthreads();

#pragma unroll
    for (int it = 0; it < 2; ++it) {
        int r = it * 16 + l15;
        const float* Arow = &A[r * 256];
        int rx = r & 7;
        f32x4 acc0 = {0.f, 0.f, 0.f, 0.f};
        f32x4 acc1 = {0.f, 0.f, 0.f, 0.f};
#pragma unroll
        for (int kb = 0; kb < 8; ++kb) {
            int c0 = kb * 8 + lhi * 2;                       // 16B-chunk index in the 1KB row
            int m0 = ((c0 & 31) ^ rx) | (c0 & 32);
            int m1 = (((c0 + 1) & 31) ^ rx) | (c0 & 32);
            f32x4 lo = *reinterpret_cast<const f32x4*>(Arow + m0 * 4);
            f32x4 hi = *reinterpret_cast<const f32x4*>(Arow + m1 * 4);
            bf16x8 af = pack8(lo, hi);
            acc0 = __builtin_amdgcn_mfma_f32_16x16x32_bf16(af, bfrag[0][kb], acc0, 0, 0, 0);
            acc1 = __builtin_amdgcn_mfma_f32_16x16x32_bf16(af, bfrag[1][kb], acc1, 0, 0, 0);
        }
        // C/D layout: col = lane&15, row = (lane>>4)*4 + reg.
#pragma unroll
        for (int i2 = 0; i2 < 4; ++i2) {
            int rr = r0base + it * 16 + lhi * 4 + i2;
            if (rr < nRows) {
                float v0 = acc0[i2] > 0.f ? acc0[i2] : 0.f;
                float v1 = acc1[i2] > 0.f ? acc1[i2] : 0.f;
                out[(size_t)rr * D + wave * 32 + l15]      = v0;
                out[(size_t)rr * D + wave * 32 + 16 + l15] = v1;
            }
        }
    }
}

// ---------------- fallback path (ws too small): atomic scatter + register GEMM ------

__global__ __launch_bounds__(256)
void scatter_edges(const float* __restrict__ X, const int* __restrict__ row,
                   const int* __restrict__ col, const float* __restrict__ val,
                   float* out, int nE)
{
    int t = blockIdx.x * 256 + threadIdx.x;
    int e = t >> 5;
    if (e >= nE) return;
    int l = t & 31;
    int r = row[e];
    int c = col[e];
    float v = val[e];
    f32x4 x = *reinterpret_cast<const f32x4*>(X + (size_t)c * D + l * 4);
    float* o = out + (size_t)r * D + l * 4;
    unsafeAtomicAdd(o + 0, x[0] * v);
    unsafeAtomicAdd(o + 1, x[1] * v);
    unsafeAtomicAdd(o + 2, x[2] * v);
    unsafeAtomicAdd(o + 3, x[3] * v);
}

__global__ __launch_bounds__(256)
void gemm_relu_fb(const float* __restrict__ Xself, const float* __restrict__ Neigh,
                  const float* __restrict__ Wself, const float* __restrict__ Wneigh,
                  float* __restrict__ out, int nRows)
{
    const int tid  = threadIdx.x;
    const int wave = tid >> 6;
    const int lane = tid & 63;
    const int l15  = lane & 15;
    const int lhi  = lane >> 4;

    bf16x8 bfrag[2][8];
#pragma unroll
    for (int n = 0; n < 2; ++n) {
        int j = wave * 32 + n * 16 + l15;
#pragma unroll
        for (int kb = 0; kb < 8; ++kb) {
            int k = kb * 32 + lhi * 8;
            const float* src = (kb < 4) ? (Wself + j * D + k)
                                        : (Wneigh + j * D + (k - 128));
            f32x4 lo = *reinterpret_cast<const f32x4*>(src);
            f32x4 hi = *reinterpret_cast<const f32x4*>(src + 4);
            bfrag[n][kb] = pack8(lo, hi);
        }
    }

    int r0base = blockIdx.x * 128;
#pragma unroll 1
    for (int it = 0; it < 8; ++it) {
        int r0 = r0base + it * 16;
        if (r0 >= nRows) break;
        const float* xrow = Xself + (size_t)(r0 + l15) * D;
        const float* nrow = Neigh + (size_t)(r0 + l15) * D;
        bf16x8 afrag[8];
#pragma unroll
        for (int kb = 0; kb < 8; ++kb) {
            const float* src = (kb < 4) ? (xrow + kb * 32 + lhi * 8)
                                        : (nrow + (kb - 4) * 32 + lhi * 8);
            f32x4 lo = *reinterpret_cast<const f32x4*>(src);
            f32x4 hi = *reinterpret_cast<const f32x4*>(src + 4);
            afrag[kb] = pack8(lo, hi);
        }
        asm volatile("s_waitcnt vmcnt(0)" ::: "memory");
        __syncthreads();

        f32x4 acc0 = {0.f, 0.f, 0.f, 0.f};
        f32x4 acc1 = {0.f, 0.f, 0.f, 0.f};
#pragma unroll
        for (int kb = 0; kb < 8; ++kb) {
            acc0 = __builtin_amdgcn_mfma_f32_16x16x32_bf16(afrag[kb], bfrag[0][kb], acc0, 0, 0, 0);
            acc1 = __builtin_amdgcn_mfma_f32_16x16x32_bf16(afrag[kb], bfrag[1][kb], acc1, 0, 0, 0);
        }
#pragma unroll
        for (int i = 0; i < 4; ++i) {
            int rr = r0 + lhi * 4 + i;
            if (rr < nRows) {
                float v0 = acc0[i] > 0.f ? acc0[i] : 0.f;
                float v1 = acc1[i] > 0.f ? acc1[i] : 0.f;
                out[(size_t)rr * D + wave * 32 + l15]      = v0;
                out[(size_t)rr * D + wave * 32 + 16 + l15] = v1;
            }
        }
    }
}

// ---------------- launch ----------------

extern "C" void kernel_launch(void* const* d_in, const int* in_sizes, int n_in,
                              void* d_out, int out_size, void* d_ws, size_t ws_size,
                              hipStream_t stream)
{
    const float* Xg_self  = (const float*)d_in[0];
    const float* Xs_self  = (const float*)d_in[1];
    const float* Xs_for_g = (const float*)d_in[2];
    const float* Xg_for_s = (const float*)d_in[3];
    const int*   row_gs   = (const int*)d_in[4];
    const int*   col_gs   = (const int*)d_in[5];
    const float* val_gs   = (const float*)d_in[6];
    const int*   row_sg   = (const int*)d_in[7];
    const int*   col_sg   = (const int*)d_in[8];
    const float* val_sg   = (const float*)d_in[9];
    const float* Wg_self  = (const float*)d_in[10];
    const float* Wg_neigh = (const float*)d_in[11];
    const float* Ws_self  = (const float*)d_in[12];
    const float* Ws_neigh = (const float*)d_in[13];

    const int NG = in_sizes[0] / D;
    const int NS = in_sizes[1] / D;
    const int E1 = in_sizes[4];
    const int E2 = in_sizes[7];
    const int N  = NG + NS;
    const int Etot = E1 + E2;

    float* out_g = (float*)d_out;
    float* out_s = out_g + (size_t)NG * D;

    // ---- workspace layout ----
    size_t off = 0;
    auto alloc = [&](size_t bytes) -> size_t {
        off = (off + 255) & ~(size_t)255;
        size_t o = off;
        off += bytes;
        return o;
    };
    size_t wcat_o   = alloc(sizeof(short) * 2 * 128 * 256);
    size_t cnt_o    = alloc(sizeof(int) * N);
    size_t start_o  = alloc(sizeof(int) * N);
    size_t cursor_o = alloc(sizeof(int) * N);
    size_t pairs_o  = alloc(sizeof(int2) * (size_t)Etot);
    size_t blk_o    = alloc(sizeof(int) * 1024);
    size_t csr_bytes = off;
    size_t neigh0_o  = alloc(sizeof(float) * (size_t)NG * D);
    size_t neigh1_o  = alloc(sizeof(float) * (size_t)NS * D);
    size_t full_bytes = off;

    char* ws = (char*)d_ws;
    bool have_csr   = ws_size >= csr_bytes;
    bool have_neigh = ws_size >= full_bytes;

    if (!have_csr) {
        hipMemsetAsync(d_out, 0, (size_t)out_size * sizeof(float), stream);
        {
            long long threads = (long long)E1 * 32;
            scatter_edges<<<(int)((threads + 255) / 256), 256, 0, stream>>>(
                Xs_for_g, row_gs, col_gs, val_gs, out_g, E1);
        }
        {
            long long threads = (long long)E2 * 32;
            scatter_edges<<<(int)((threads + 255) / 256), 256, 0, stream>>>(
                Xg_for_s, row_sg, col_sg, val_sg, out_s, E2);
        }
        gemm_relu_fb<<<(NG + 127) / 128, 256, 0, stream>>>(Xg_self, out_g, Wg_self, Wg_neigh, out_g, NG);
        gemm_relu_fb<<<(NS + 127) / 128, 256, 0, stream>>>(Xs_self, out_s, Ws_self, Ws_neigh, out_s, NS);
        return;
    }

    short* wcat  = (short*)(ws + wcat_o);
    int* cnt     = (int*)(ws + cnt_o);
    int* start   = (int*)(ws + start_o);
    int* cursor  = (int*)(ws + cursor_o);
    int2* pairs  = (int2*)(ws + pairs_o);
    int* blk     = (int*)(ws + blk_o);
    float* neigh0 = have_neigh ? (float*)(ws + neigh0_o) : out_g;
    float* neigh1 = have_neigh ? (float*)(ws + neigh1_o) : out_s;

    wprep_kernel<<<32, 256, 0, stream>>>(Wg_self, Wg_neigh, Ws_self, Ws_neigh, wcat);
    hipMemsetAsync(cnt, 0, sizeof(int) * N, stream);
    hist2_kernel<<<(Etot + 255) / 256, 256, 0, stream>>>(row_gs, E1, row_sg, NG, cnt, Etot);
    int nb = (N + 1023) / 1024;   // 196 <= 256
    scan1_kernel<<<nb, 256, 0, stream>>>(cnt, start, blk, N);
    scan2_kernel<<<1, 256, 0, stream>>>(blk, nb);
    scan3_kernel<<<(N + 255) / 256, 256, 0, stream>>>(start, cursor, blk, N);
    fill2_kernel<<<(Etot + 255) / 256, 256, 0, stream>>>(
        row_gs, col_gs, val_gs, E1, row_sg, col_sg, val_sg, NG, cursor, pairs, Etot);
    gather_kernel<<<(N * 64 + 255) / 256, 256, 0, stream>>>(
        Xs_for_g, Xg_for_s, start, cnt, pairs, neigh0, neigh1, NG, N);

    int blocks0 = (NG + 31) / 32, blocks1 = (NS + 31) / 32;
    gemm_relu_main<<<blocks0 + blocks1, 256, 0, stream>>>(
        Xg_self, neigh0, out_g, NG,
        Xs_self, neigh1, out_s, NS, wcat);
}

// Round 5
// 318.980 us; speedup vs baseline: 7.3350x; 1.1169x over previous
//
#include <hip/hip_runtime.h>
#include <hip/hip_bf16.h>
#include <stdint.h>

typedef __attribute__((ext_vector_type(4))) float f32x4;
typedef __attribute__((ext_vector_type(2))) float f32x2;
typedef __attribute__((ext_vector_type(8))) short bf16x8;

#define D 128

__device__ inline short f2bf(float x) {
    __hip_bfloat16 h = __float2bfloat16(x);
    return __builtin_bit_cast(short, h);
}

__device__ inline bf16x8 pack8(f32x4 lo, f32x4 hi) {
    bf16x8 b;
    b[0] = f2bf(lo[0]); b[1] = f2bf(lo[1]); b[2] = f2bf(lo[2]); b[3] = f2bf(lo[3]);
    b[4] = f2bf(hi[0]); b[5] = f2bf(hi[1]); b[6] = f2bf(hi[2]); b[7] = f2bf(hi[3]);
    return b;
}

__device__ inline unsigned int pack2bf(float a, float b) {
    unsigned int ua = (unsigned int)(unsigned short)f2bf(a);
    unsigned int ub = (unsigned int)(unsigned short)f2bf(b);
    return ua | (ub << 16);
}

// ---------------- X-for tables: f32 -> bf16 (read once here, read ~6.4x in gather) ----

__global__ __launch_bounds__(256)
void xprep_kernel(const float* __restrict__ src, unsigned short* __restrict__ dst, int n8)
{
    int i = blockIdx.x * 256 + threadIdx.x;
    if (i >= n8) return;
    f32x4 lo = *reinterpret_cast<const f32x4*>(src + (size_t)i * 8);
    f32x4 hi = *reinterpret_cast<const f32x4*>(src + (size_t)i * 8 + 4);
    *reinterpret_cast<bf16x8*>(dst + (size_t)i * 8) = pack8(lo, hi);
}

// ---------------- weight pre-pack: Wcat[dir][j][k] bf16, k<128 = Wself, else Wneigh ----

__global__ __launch_bounds__(256)
void wprep_kernel(const float* __restrict__ Wg_self, const float* __restrict__ Wg_neigh,
                  const float* __restrict__ Ws_self, const float* __restrict__ Ws_neigh,
                  short* __restrict__ Wcat)
{
    int t = blockIdx.x * 256 + threadIdx.x;
    if (t >= 2 * 128 * 32) return;
    int dir = t >> 12;
    int rem = t & 4095;
    int j = rem >> 5;
    int k = (rem & 31) * 8;
    const float* Wself  = dir ? Ws_self  : Wg_self;
    const float* Wneigh = dir ? Ws_neigh : Wg_neigh;
    const float* src = (k < 128) ? (Wself + j * D + k) : (Wneigh + j * D + (k - 128));
    f32x4 lo = *reinterpret_cast<const f32x4*>(src);
    f32x4 hi = *reinterpret_cast<const f32x4*>(src + 4);
    *reinterpret_cast<bf16x8*>(Wcat + (size_t)dir * 32768 + j * 256 + k) = pack8(lo, hi);
}

// ---------------- CSR build (both directions share one index space [0, NG+NS)) ----

__global__ __launch_bounds__(256)
void hist2_kernel(const int* __restrict__ rowA, int EA,
                  const int* __restrict__ rowB, int NGoff,
                  int* __restrict__ cnt, int Etot)
{
    int e = blockIdx.x * 256 + threadIdx.x;
    if (e >= Etot) return;
    int r = (e < EA) ? rowA[e] : (rowB[e - EA] + NGoff);
    atomicAdd(&cnt[r], 1);
}

__global__ __launch_bounds__(256)
void scan1_kernel(const int* __restrict__ cnt, int* __restrict__ part,
                  int* __restrict__ blksums, int N)
{
    __shared__ int wsum[4];
    int t = threadIdx.x;
    int base = blockIdx.x * 1024 + t * 4;
    int v0 = base + 0 < N ? cnt[base + 0] : 0;
    int v1 = base + 1 < N ? cnt[base + 1] : 0;
    int v2 = base + 2 < N ? cnt[base + 2] : 0;
    int v3 = base + 3 < N ? cnt[base + 3] : 0;
    int s = v0 + v1 + v2 + v3;
    int lane = t & 63, w = t >> 6;
    int x = s;
#pragma unroll
    for (int off = 1; off < 64; off <<= 1) {
        int y = __shfl_up(x, off);
        if (lane >= off) x += y;
    }
    if (lane == 63) wsum[w] = x;
    __syncthreads();
    int woff = 0;
    for (int i = 0; i < w; ++i) woff += wsum[i];
    int incl = x + woff;
    int excl = incl - s;
    if (base + 0 < N) part[base + 0] = excl;
    if (base + 1 < N) part[base + 1] = excl + v0;
    if (base + 2 < N) part[base + 2] = excl + v0 + v1;
    if (base + 3 < N) part[base + 3] = excl + v0 + v1 + v2;
    if (t == 255) blksums[blockIdx.x] = incl;
}

__global__ __launch_bounds__(256)
void scan2_kernel(int* __restrict__ blksums, int nb)
{
    __shared__ int wsum[4];
    int t = threadIdx.x;
    int v = t < nb ? blksums[t] : 0;
    int lane = t & 63, w = t >> 6;
    int x = v;
#pragma unroll
    for (int off = 1; off < 64; off <<= 1) {
        int y = __shfl_up(x, off);
        if (lane >= off) x += y;
    }
    if (lane == 63) wsum[w] = x;
    __syncthreads();
    int woff = 0;
    for (int i = 0; i < w; ++i) woff += wsum[i];
    int excl = x + woff - v;
    if (t < nb) blksums[t] = excl;
}

__global__ __launch_bounds__(256)
void scan3_kernel(int* __restrict__ start, int* __restrict__ cursor,
                  const int* __restrict__ blksums, int N)
{
    int i = blockIdx.x * 256 + threadIdx.x;
    if (i < N) {
        int v = start[i] + blksums[i >> 10];
        start[i] = v;
        cursor[i] = v;
    }
}

__global__ __launch_bounds__(256)
void fill2_kernel(const int* __restrict__ rowA, const int* __restrict__ colA,
                  const float* __restrict__ valA, int EA,
                  const int* __restrict__ rowB, const int* __restrict__ colB,
                  const float* __restrict__ valB, int NGoff,
                  int* __restrict__ cursor, int2* __restrict__ pairs, int Etot)
{
    int e = blockIdx.x * 256 + threadIdx.x;
    if (e >= Etot) return;
    int r, c; float v;
    if (e < EA) { r = rowA[e]; c = colA[e]; v = valA[e]; }
    else { int e2 = e - EA; r = rowB[e2] + NGoff; c = colB[e2]; v = valB[e2]; }
    int p = atomicAdd(&cursor[r], 1);
    pairs[p] = make_int2(c, __float_as_int(v));
}

// ---------------- fused gather + GEMM + relu ----------------
// Block = 256 thr / 4 waves / 32 rows. Phase 1: gather neigh rows from bf16 X table
// (2 rows per wave in parallel, 32 lanes each, bf16x4 per lane) and convert Xself,
// writing the combined A-row [Xself|neigh] as bf16 into LDS with a 16B-chunk XOR
// swizzle (chunk ^ (row&7)) applied identically on write and read (both-sides rule).
// Phase 2: MFMA from LDS with pre-packed weight fragments. No neigh global round-trip.
__global__ __launch_bounds__(256)
void fused_kernel(const unsigned short* __restrict__ X16_0,
                  const unsigned short* __restrict__ X16_1,
                  const float* __restrict__ Xself0, float* __restrict__ out0, int n0,
                  const float* __restrict__ Xself1, float* __restrict__ out1, int n1,
                  const int* __restrict__ start, const int* __restrict__ cnt,
                  const int2* __restrict__ pairs, const short* __restrict__ Wcat)
{
    __shared__ bf16x8 Ab[32 * 32];   // 32 rows x 32 chunks(16B) = 16 KiB
    const int ROWS = 32;
    int blocks0 = (n0 + ROWS - 1) / ROWS;

    const unsigned short* X16; const float* Xself; float* out;
    int nRows, r0base, csr0; const short* Wb;
    if ((int)blockIdx.x < blocks0) {
        X16 = X16_0; Xself = Xself0; out = out0; nRows = n0;
        r0base = blockIdx.x * ROWS; csr0 = 0; Wb = Wcat;
    } else {
        X16 = X16_1; Xself = Xself1; out = out1; nRows = n1;
        r0base = ((int)blockIdx.x - blocks0) * ROWS; csr0 = n0; Wb = Wcat + 32768;
    }

    const int tid = threadIdx.x, wave = tid >> 6, lane = tid & 63;
    const int l15 = lane & 15, lhi = lane >> 4;
    const int l31 = lane & 31, half = lane >> 5;

    unsigned int* Aw   = (unsigned int*)Ab;
    uint2*        A64  = (uint2*)Ab;

    // ---- Phase 1: gather (2 rows per wave in parallel) ----
#pragma unroll 1
    for (int i = 0; i < 4; ++i) {
        int r = wave * 8 + i * 2 + half;       // local row 0..31, per half-wave
        int R = r0base + r;
        if (R >= nRows) R = nRows - 1;
        int gid = csr0 + R;
        int s = start[gid];
        int n = cnt[gid];                      // uniform per half-wave (not per wave)
        f32x4 acc = {0.f, 0.f, 0.f, 0.f};
        int j = 0;
        for (; j + 4 <= n; j += 4) {
            int2 p[4]; uint2 xb[4];
#pragma unroll
            for (int u = 0; u < 4; ++u) {
                p[u] = pairs[s + j + u];
                xb[u] = *reinterpret_cast<const uint2*>(X16 + (size_t)p[u].x * D + l31 * 4);
            }
#pragma unroll
            for (int u = 0; u < 4; ++u) {
                float v = __int_as_float(p[u].y);
                acc[0] += __uint_as_float(xb[u].x << 16) * v;
                acc[1] += __uint_as_float(xb[u].x & 0xffff0000u) * v;
                acc[2] += __uint_as_float(xb[u].y << 16) * v;
                acc[3] += __uint_as_float(xb[u].y & 0xffff0000u) * v;
            }
        }
        for (; j < n; ++j) {
            int2 p = pairs[s + j];
            uint2 xb = *reinterpret_cast<const uint2*>(X16 + (size_t)p.x * D + l31 * 4);
            float v = __int_as_float(p.y);
            acc[0] += __uint_as_float(xb.x << 16) * v;
            acc[1] += __uint_as_float(xb.x & 0xffff0000u) * v;
            acc[2] += __uint_as_float(xb.y << 16) * v;
            acc[3] += __uint_as_float(xb.y & 0xffff0000u) * v;
        }
        // Xself row (f32) -> bf16
        f32x4 xs = *reinterpret_cast<const f32x4*>(Xself + (size_t)R * D + l31 * 4);
        uint2 sb = { pack2bf(xs[0], xs[1]),  pack2bf(xs[2], xs[3]) };
        uint2 nb = { pack2bf(acc[0], acc[1]), pack2bf(acc[2], acc[3]) };
        // LDS write, chunk-XOR swizzled. element chunk: Xself half = l31>>1, neigh = 16+(l31>>1)
        int rx = r & 7;
        int cS = (l31 >> 1) ^ rx;
        int cN = 16 + ((l31 >> 1) ^ rx);
        A64[r * 64 + cS * 2 + (l31 & 1)] = sb;
        A64[r * 64 + cN * 2 + (l31 & 1)] = nb;
    }

    // ---- weight fragments (L2-resident; loads overlap barrier wait) ----
    bf16x8 bfrag[2][8];
#pragma unroll
    for (int n = 0; n < 2; ++n) {
        int j = wave * 32 + n * 16 + l15;
#pragma unroll
        for (int kb = 0; kb < 8; ++kb)
            bfrag[n][kb] = *reinterpret_cast<const bf16x8*>(
                Wb + (size_t)j * 256 + kb * 32 + lhi * 8);
    }

    __syncthreads();

    // ---- Phase 2: MFMA + relu + store ----
#pragma unroll
    for (int it = 0; it < 2; ++it) {
        int r = it * 16 + l15;
        int rx = r & 7;
        f32x4 acc0 = {0.f, 0.f, 0.f, 0.f};
        f32x4 acc1 = {0.f, 0.f, 0.f, 0.f};
#pragma unroll
        for (int kb = 0; kb < 8; ++kb) {
            int c = kb * 4 + lhi;                 // 16B chunk 0..31 (bit4 = neigh half)
            bf16x8 af = Ab[r * 32 + (c ^ rx)];    // rx<8 flips only low 3 bits
            acc0 = __builtin_amdgcn_mfma_f32_16x16x32_bf16(af, bfrag[0][kb], acc0, 0, 0, 0);
            acc1 = __builtin_amdgcn_mfma_f32_16x16x32_bf16(af, bfrag[1][kb], acc1, 0, 0, 0);
        }
        // C/D layout: col = lane&15, row = (lane>>4)*4 + reg.
#pragma unroll
        for (int i2 = 0; i2 < 4; ++i2) {
            int rr = r0base + it * 16 + lhi * 4 + i2;
            if (rr < nRows) {
                float v0 = acc0[i2] > 0.f ? acc0[i2] : 0.f;
                float v1 = acc1[i2] > 0.f ? acc1[i2] : 0.f;
                out[(size_t)rr * D + wave * 32 + l15]      = v0;
                out[(size_t)rr * D + wave * 32 + 16 + l15] = v1;
            }
        }
    }
}

// ---------------- fallback path (ws too small): atomic scatter + register GEMM ------

__global__ __launch_bounds__(256)
void scatter_edges(const float* __restrict__ X, const int* __restrict__ row,
                   const int* __restrict__ col, const float* __restrict__ val,
                   float* out, int nE)
{
    int t = blockIdx.x * 256 + threadIdx.x;
    int e = t >> 5;
    if (e >= nE) return;
    int l = t & 31;
    int r = row[e];
    int c = col[e];
    float v = val[e];
    f32x4 x = *reinterpret_cast<const f32x4*>(X + (size_t)c * D + l * 4);
    float* o = out + (size_t)r * D + l * 4;
    unsafeAtomicAdd(o + 0, x[0] * v);
    unsafeAtomicAdd(o + 1, x[1] * v);
    unsafeAtomicAdd(o + 2, x[2] * v);
    unsafeAtomicAdd(o + 3, x[3] * v);
}

__global__ __launch_bounds__(256)
void gemm_relu_fb(const float* __restrict__ Xself, const float* __restrict__ Neigh,
                  const float* __restrict__ Wself, const float* __restrict__ Wneigh,
                  float* __restrict__ out, int nRows)
{
    const int tid  = threadIdx.x;
    const int wave = tid >> 6;
    const int lane = tid & 63;
    const int l15  = lane & 15;
    const int lhi  = lane >> 4;

    bf16x8 bfrag[2][8];
#pragma unroll
    for (int n = 0; n < 2; ++n) {
        int j = wave * 32 + n * 16 + l15;
#pragma unroll
        for (int kb = 0; kb < 8; ++kb) {
            int k = kb * 32 + lhi * 8;
            const float* src = (kb < 4) ? (Wself + j * D + k)
                                        : (Wneigh + j * D + (k - 128));
            f32x4 lo = *reinterpret_cast<const f32x4*>(src);
            f32x4 hi = *reinterpret_cast<const f32x4*>(src + 4);
            bfrag[n][kb] = pack8(lo, hi);
        }
    }

    int r0base = blockIdx.x * 128;
#pragma unroll 1
    for (int it = 0; it < 8; ++it) {
        int r0 = r0base + it * 16;
        if (r0 >= nRows) break;
        const float* xrow = Xself + (size_t)(r0 + l15) * D;
        const float* nrow = Neigh + (size_t)(r0 + l15) * D;
        bf16x8 afrag[8];
#pragma unroll
        for (int kb = 0; kb < 8; ++kb) {
            const float* src = (kb < 4) ? (xrow + kb * 32 + lhi * 8)
                                        : (nrow + (kb - 4) * 32 + lhi * 8);
            f32x4 lo = *reinterpret_cast<const f32x4*>(src);
            f32x4 hi = *reinterpret_cast<const f32x4*>(src + 4);
            afrag[kb] = pack8(lo, hi);
        }
        asm volatile("s_waitcnt vmcnt(0)" ::: "memory");
        __syncthreads();

        f32x4 acc0 = {0.f, 0.f, 0.f, 0.f};
        f32x4 acc1 = {0.f, 0.f, 0.f, 0.f};
#pragma unroll
        for (int kb = 0; kb < 8; ++kb) {
            acc0 = __builtin_amdgcn_mfma_f32_16x16x32_bf16(afrag[kb], bfrag[0][kb], acc0, 0, 0, 0);
            acc1 = __builtin_amdgcn_mfma_f32_16x16x32_bf16(afrag[kb], bfrag[1][kb], acc1, 0, 0, 0);
        }
#pragma unroll
        for (int i = 0; i < 4; ++i) {
            int rr = r0 + lhi * 4 + i;
            if (rr < nRows) {
                float v0 = acc0[i] > 0.f ? acc0[i] : 0.f;
                float v1 = acc1[i] > 0.f ? acc1[i] : 0.f;
                out[(size_t)rr * D + wave * 32 + l15]      = v0;
                out[(size_t)rr * D + wave * 32 + 16 + l15] = v1;
            }
        }
    }
}

// ---------------- launch ----------------

extern "C" void kernel_launch(void* const* d_in, const int* in_sizes, int n_in,
                              void* d_out, int out_size, void* d_ws, size_t ws_size,
                              hipStream_t stream)
{
    const float* Xg_self  = (const float*)d_in[0];
    const float* Xs_self  = (const float*)d_in[1];
    const float* Xs_for_g = (const float*)d_in[2];
    const float* Xg_for_s = (const float*)d_in[3];
    const int*   row_gs   = (const int*)d_in[4];
    const int*   col_gs   = (const int*)d_in[5];
    const float* val_gs   = (const float*)d_in[6];
    const int*   row_sg   = (const int*)d_in[7];
    const int*   col_sg   = (const int*)d_in[8];
    const float* val_sg   = (const float*)d_in[9];
    const float* Wg_self  = (const float*)d_in[10];
    const float* Wg_neigh = (const float*)d_in[11];
    const float* Ws_self  = (const float*)d_in[12];
    const float* Ws_neigh = (const float*)d_in[13];

    const int NG = in_sizes[0] / D;
    const int NS = in_sizes[1] / D;
    const int E1 = in_sizes[4];
    const int E2 = in_sizes[7];
    const int N  = NG + NS;
    const int Etot = E1 + E2;

    float* out_g = (float*)d_out;
    float* out_s = out_g + (size_t)NG * D;

    // ---- workspace layout ----
    size_t off = 0;
    auto alloc = [&](size_t bytes) -> size_t {
        off = (off + 255) & ~(size_t)255;
        size_t o = off;
        off += bytes;
        return o;
    };
    size_t x16g_o   = alloc(sizeof(short) * (size_t)NG * D);   // bf16 Xs_for_g
    size_t x16s_o   = alloc(sizeof(short) * (size_t)NS * D);   // bf16 Xg_for_s
    size_t wcat_o   = alloc(sizeof(short) * 2 * 128 * 256);
    size_t cnt_o    = alloc(sizeof(int) * N);
    size_t start_o  = alloc(sizeof(int) * N);
    size_t cursor_o = alloc(sizeof(int) * N);
    size_t pairs_o  = alloc(sizeof(int2) * (size_t)Etot);
    size_t blk_o    = alloc(sizeof(int) * 1024);
    size_t need_bytes = off;

    char* ws = (char*)d_ws;

    if (ws_size < need_bytes) {
        // ---- fallback: atomic scatter + in-place register GEMM ----
        hipMemsetAsync(d_out, 0, (size_t)out_size * sizeof(float), stream);
        {
            long long threads = (long long)E1 * 32;
            scatter_edges<<<(int)((threads + 255) / 256), 256, 0, stream>>>(
                Xs_for_g, row_gs, col_gs, val_gs, out_g, E1);
        }
        {
            long long threads = (long long)E2 * 32;
            scatter_edges<<<(int)((threads + 255) / 256), 256, 0, stream>>>(
                Xg_for_s, row_sg, col_sg, val_sg, out_s, E2);
        }
        gemm_relu_fb<<<(NG + 127) / 128, 256, 0, stream>>>(Xg_self, out_g, Wg_self, Wg_neigh, out_g, NG);
        gemm_relu_fb<<<(NS + 127) / 128, 256, 0, stream>>>(Xs_self, out_s, Ws_self, Ws_neigh, out_s, NS);
        return;
    }

    unsigned short* x16g = (unsigned short*)(ws + x16g_o);
    unsigned short* x16s = (unsigned short*)(ws + x16s_o);
    short* wcat  = (short*)(ws + wcat_o);
    int* cnt     = (int*)(ws + cnt_o);
    int* start   = (int*)(ws + start_o);
    int* cursor  = (int*)(ws + cursor_o);
    int2* pairs  = (int2*)(ws + pairs_o);
    int* blk     = (int*)(ws + blk_o);

    xprep_kernel<<<(NG * D / 8 + 255) / 256, 256, 0, stream>>>(Xs_for_g, x16g, NG * D / 8);
    xprep_kernel<<<(NS * D / 8 + 255) / 256, 256, 0, stream>>>(Xg_for_s, x16s, NS * D / 8);
    wprep_kernel<<<32, 256, 0, stream>>>(Wg_self, Wg_neigh, Ws_self, Ws_neigh, wcat);

    hipMemsetAsync(cnt, 0, sizeof(int) * N, stream);
    hist2_kernel<<<(Etot + 255) / 256, 256, 0, stream>>>(row_gs, E1, row_sg, NG, cnt, Etot);
    int nb = (N + 1023) / 1024;   // 196 <= 256
    scan1_kernel<<<nb, 256, 0, stream>>>(cnt, start, blk, N);
    scan2_kernel<<<1, 256, 0, stream>>>(blk, nb);
    scan3_kernel<<<(N + 255) / 256, 256, 0, stream>>>(start, cursor, blk, N);
    fill2_kernel<<<(Etot + 255) / 256, 256, 0, stream>>>(
        row_gs, col_gs, val_gs, E1, row_sg, col_sg, val_sg, NG, cursor, pairs, Etot);

    int blocks0 = (NG + 31) / 32, blocks1 = (NS + 31) / 32;
    fused_kernel<<<blocks0 + blocks1, 256, 0, stream>>>(
        x16g, x16s,
        Xg_self, out_g, NG,
        Xs_self, out_s, NS,
        start, cnt, pairs, wcat);
}

// Round 6
// 297.644 us; speedup vs baseline: 7.8608x; 1.0717x over previous
//
#include <hip/hip_runtime.h>
#include <hip/hip_bf16.h>
#include <stdint.h>

typedef __attribute__((ext_vector_type(4))) float f32x4;
typedef __attribute__((ext_vector_type(8))) short bf16x8;

#define D 128
#define GLOBAL_AS __attribute__((address_space(1)))
#define LDS_AS __attribute__((address_space(3)))

__device__ inline short f2bf(float x) {
    __hip_bfloat16 h = __float2bfloat16(x);
    return __builtin_bit_cast(short, h);
}

__device__ inline bf16x8 pack8(f32x4 lo, f32x4 hi) {
    bf16x8 b;
    b[0] = f2bf(lo[0]); b[1] = f2bf(lo[1]); b[2] = f2bf(lo[2]); b[3] = f2bf(lo[3]);
    b[4] = f2bf(hi[0]); b[5] = f2bf(hi[1]); b[6] = f2bf(hi[2]); b[7] = f2bf(hi[3]);
    return b;
}

__device__ inline unsigned int pack2bf(float a, float b) {
    unsigned int ua = (unsigned int)(unsigned short)f2bf(a);
    unsigned int ub = (unsigned int)(unsigned short)f2bf(b);
    return ua | (ub << 16);
}

// ---------------- merged prep: bf16-ify both X tables + pack weights + histogram ----

__global__ __launch_bounds__(256)
void prep_kernel(const float* __restrict__ Xa, const float* __restrict__ Xb,
                 unsigned short* __restrict__ x16a, unsigned short* __restrict__ x16b,
                 const float* __restrict__ Wg_self, const float* __restrict__ Wg_neigh,
                 const float* __restrict__ Ws_self, const float* __restrict__ Ws_neigh,
                 short* __restrict__ Wcat,
                 const int* __restrict__ rowA, int EA,
                 const int* __restrict__ rowB, int NGoff,
                 int* __restrict__ cnt,
                 int n8a, int n8b, int Etot)
{
    int t = blockIdx.x * 256 + threadIdx.x;
    if (t < n8a) {
        f32x4 lo = *reinterpret_cast<const f32x4*>(Xa + (size_t)t * 8);
        f32x4 hi = *reinterpret_cast<const f32x4*>(Xa + (size_t)t * 8 + 4);
        *reinterpret_cast<bf16x8*>(x16a + (size_t)t * 8) = pack8(lo, hi);
        return;
    }
    t -= n8a;
    if (t < n8b) {
        f32x4 lo = *reinterpret_cast<const f32x4*>(Xb + (size_t)t * 8);
        f32x4 hi = *reinterpret_cast<const f32x4*>(Xb + (size_t)t * 8 + 4);
        *reinterpret_cast<bf16x8*>(x16b + (size_t)t * 8) = pack8(lo, hi);
        return;
    }
    t -= n8b;
    if (t < 2 * 128 * 32) {
        int dir = t >> 12;
        int rem = t & 4095;
        int j = rem >> 5;
        int k = (rem & 31) * 8;
        const float* Wself  = dir ? Ws_self  : Wg_self;
        const float* Wneigh = dir ? Ws_neigh : Wg_neigh;
        const float* src = (k < 128) ? (Wself + j * D + k) : (Wneigh + j * D + (k - 128));
        f32x4 lo = *reinterpret_cast<const f32x4*>(src);
        f32x4 hi = *reinterpret_cast<const f32x4*>(src + 4);
        *reinterpret_cast<bf16x8*>(Wcat + (size_t)dir * 32768 + j * 256 + k) = pack8(lo, hi);
        return;
    }
    t -= 2 * 128 * 32;
    if (t < Etot) {
        int r = (t < EA) ? rowA[t] : (rowB[t - EA] + NGoff);
        atomicAdd(&cnt[r], 1);
    }
}

// ---------------- scans ----------------

__global__ __launch_bounds__(256)
void scan1_kernel(const int* __restrict__ cnt, int* __restrict__ part,
                  int* __restrict__ blksums, int N)
{
    __shared__ int wsum[4];
    int t = threadIdx.x;
    int base = blockIdx.x * 1024 + t * 4;
    int v0 = base + 0 < N ? cnt[base + 0] : 0;
    int v1 = base + 1 < N ? cnt[base + 1] : 0;
    int v2 = base + 2 < N ? cnt[base + 2] : 0;
    int v3 = base + 3 < N ? cnt[base + 3] : 0;
    int s = v0 + v1 + v2 + v3;
    int lane = t & 63, w = t >> 6;
    int x = s;
#pragma unroll
    for (int off = 1; off < 64; off <<= 1) {
        int y = __shfl_up(x, off);
        if (lane >= off) x += y;
    }
    if (lane == 63) wsum[w] = x;
    __syncthreads();
    int woff = 0;
    for (int i = 0; i < w; ++i) woff += wsum[i];
    int incl = x + woff;
    int excl = incl - s;
    if (base + 0 < N) part[base + 0] = excl;
    if (base + 1 < N) part[base + 1] = excl + v0;
    if (base + 2 < N) part[base + 2] = excl + v0 + v1;
    if (base + 3 < N) part[base + 3] = excl + v0 + v1 + v2;
    if (t == 255) blksums[blockIdx.x] = incl;
}

__global__ __launch_bounds__(256)
void scan2_kernel(int* __restrict__ blksums, int nb)
{
    __shared__ int wsum[4];
    int t = threadIdx.x;
    int v = t < nb ? blksums[t] : 0;
    int lane = t & 63, w = t >> 6;
    int x = v;
#pragma unroll
    for (int off = 1; off < 64; off <<= 1) {
        int y = __shfl_up(x, off);
        if (lane >= off) x += y;
    }
    if (lane == 63) wsum[w] = x;
    __syncthreads();
    int woff = 0;
    for (int i = 0; i < w; ++i) woff += wsum[i];
    int excl = x + woff - v;
    if (t < nb) blksums[t] = excl;
}

__global__ __launch_bounds__(256)
void scan3_kernel(int* __restrict__ cursor, const int* __restrict__ blksums, int N)
{
    int i = blockIdx.x * 256 + threadIdx.x;
    if (i < N) cursor[i] += blksums[i >> 10];
}

__global__ __launch_bounds__(256)
void fill2_kernel(const int* __restrict__ rowA, const int* __restrict__ colA,
                  const float* __restrict__ valA, int EA,
                  const int* __restrict__ rowB, const int* __restrict__ colB,
                  const float* __restrict__ valB, int NGoff,
                  int* __restrict__ cursor, int2* __restrict__ pairs, int Etot)
{
    int e = blockIdx.x * 256 + threadIdx.x;
    if (e >= Etot) return;
    int r, c; float v;
    if (e < EA) { r = rowA[e]; c = colA[e]; v = valA[e]; }
    else { int e2 = e - EA; r = rowB[e2] + NGoff; c = colB[e2]; v = valB[e2]; }
    int p = atomicAdd(&cursor[r], 1);
    pairs[p] = make_int2(c, __float_as_int(v));
}

// ---------------- fused gather + GEMM + relu ----------------
// 512 thr / 8 waves / 32 rows per block.
//  - Xself rows staged f32 into As via global_load_lds at entry (overlaps gather);
//    chunk-XOR swizzle applied on the per-lane GLOBAL source (rule #21), read back
//    with the same involution.
//  - Gather: 16 half-wave streams x 2 rows; per row, predicated groups of 8 edges
//    (clamped idx, zeroed val) -> 8 independent 256B loads in flight, no serial tail.
//    Result packed bf16 into Ab (chunk-XOR swizzled write, matching read).
//  - Phase 2: 8 waves x one 16-col tile; afrag kb<4 from As (pack to bf16), kb>=4
//    from Ab; 128 MFMAs/block.
__global__ __launch_bounds__(512, 6)
void fused_kernel(const unsigned short* __restrict__ X16_0,
                  const unsigned short* __restrict__ X16_1,
                  const float* __restrict__ Xself0, float* __restrict__ out0, int n0,
                  const float* __restrict__ Xself1, float* __restrict__ out1, int n1,
                  const int* __restrict__ cnt, const int* __restrict__ endpos,
                  const int2* __restrict__ pairs, const short* __restrict__ Wcat)
{
    __shared__ float  As[32 * 128];   // 16 KiB: f32 Xself rows (32 x 512B)
    __shared__ bf16x8 Ab[32 * 16];    // 8 KiB: bf16 neigh rows (32 x 16 chunks)

    const int ROWS = 32;
    int blocks0 = (n0 + ROWS - 1) / ROWS;

    const unsigned short* X16; const float* Xself; float* out;
    int nRows, r0base, csr0; const short* Wb;
    if ((int)blockIdx.x < blocks0) {
        X16 = X16_0; Xself = Xself0; out = out0; nRows = n0;
        r0base = blockIdx.x * ROWS; csr0 = 0; Wb = Wcat;
    } else {
        X16 = X16_1; Xself = Xself1; out = out1; nRows = n1;
        r0base = ((int)blockIdx.x - blocks0) * ROWS; csr0 = n0; Wb = Wcat + 32768;
    }

    const int tid  = threadIdx.x;
    const int wave = tid >> 6, lane = tid & 63;
    const int l15  = lane & 15, lhi = lane >> 4;
    const int l31  = lane & 31;
    const int hw   = tid >> 5;          // half-wave stream id 0..15

    // ---- stage Xself (f32) into As; 2 instrs/wave, covers 4 rows each ----
#pragma unroll
    for (int q = 0; q < 2; ++q) {
        int rs = wave * 4 + q * 2 + (lane >> 5);
        int R = r0base + rs; if (R > nRows - 1) R = nRows - 1;
        const float* g = Xself + (size_t)R * D + (((lane & 31) ^ (rs & 7)) << 2);
        __builtin_amdgcn_global_load_lds((const GLOBAL_AS uint32_t*)g,
                                         (LDS_AS uint32_t*)(&As[(wave * 4 + q * 2) * 128]),
                                         16, 0, 0);
    }

    // ---- gather ----
    uint2* Ab64 = (uint2*)Ab;
#pragma unroll 1
    for (int ii = 0; ii < 2; ++ii) {
        int r = hw * 2 + ii;
        int R = r0base + r; if (R > nRows - 1) R = nRows - 1;
        int gid = csr0 + R;
        int n = cnt[gid];
        int s = endpos[gid] - n;
        f32x4 acc = {0.f, 0.f, 0.f, 0.f};
#pragma unroll 1
        for (int j = 0; j < n; j += 8) {
            int2 p[8]; uint2 xb[8];
#pragma unroll
            for (int u = 0; u < 8; ++u) {
                int idx = (j + u < n) ? j + u : n - 1;
                p[u] = pairs[s + idx];
            }
#pragma unroll
            for (int u = 0; u < 8; ++u)
                xb[u] = *reinterpret_cast<const uint2*>(X16 + (size_t)p[u].x * D + l31 * 4);
#pragma unroll
            for (int u = 0; u < 8; ++u) {
                float v = (j + u < n) ? __int_as_float(p[u].y) : 0.f;
                acc[0] += __uint_as_float(xb[u].x << 16) * v;
                acc[1] += __uint_as_float(xb[u].x & 0xffff0000u) * v;
                acc[2] += __uint_as_float(xb[u].y << 16) * v;
                acc[3] += __uint_as_float(xb[u].y & 0xffff0000u) * v;
            }
        }
        uint2 nb = { pack2bf(acc[0], acc[1]), pack2bf(acc[2], acc[3]) };
        int cn = (l31 >> 1) ^ (r & 7);
        Ab64[r * 32 + cn * 2 + (l31 & 1)] = nb;
    }

    // ---- weight fragments (L2-resident; overlap barrier wait) ----
    bf16x8 bfrag[8];
    {
        int j = wave * 16 + l15;
#pragma unroll
        for (int kb = 0; kb < 8; ++kb)
            bfrag[kb] = *reinterpret_cast<const bf16x8*>(
                Wb + (size_t)j * 256 + kb * 32 + lhi * 8);
    }

    __syncthreads();

    // ---- MFMA + relu + store; wave w owns cols [16w, 16w+16) ----
#pragma unroll
    for (int it = 0; it < 2; ++it) {
        int r = it * 16 + l15;
        int rx = r & 7;
        f32x4 acc = {0.f, 0.f, 0.f, 0.f};
#pragma unroll
        for (int kb = 0; kb < 8; ++kb) {
            bf16x8 af;
            if (kb < 4) {
                int c0 = kb * 8 + lhi * 2;
                f32x4 lo = *reinterpret_cast<const f32x4*>(&As[r * 128 + ((c0 ^ rx) << 2)]);
                f32x4 hi = *reinterpret_cast<const f32x4*>(&As[r * 128 + (((c0 + 1) ^ rx) << 2)]);
                af = pack8(lo, hi);
            } else {
                int cn = (kb - 4) * 4 + lhi;
                af = Ab[r * 16 + (cn ^ rx)];
            }
            acc = __builtin_amdgcn_mfma_f32_16x16x32_bf16(af, bfrag[kb], acc, 0, 0, 0);
        }
        // C/D layout: col = lane&15, row = (lane>>4)*4 + reg.
#pragma unroll
        for (int i2 = 0; i2 < 4; ++i2) {
            int rr = r0base + it * 16 + lhi * 4 + i2;
            if (rr < nRows) {
                float v = acc[i2] > 0.f ? acc[i2] : 0.f;
                out[(size_t)rr * D + wave * 16 + l15] = v;
            }
        }
    }
}

// ---------------- fallback path (ws too small): atomic scatter + register GEMM ------

__global__ __launch_bounds__(256)
void scatter_edges(const float* __restrict__ X, const int* __restrict__ row,
                   const int* __restrict__ col, const float* __restrict__ val,
                   float* out, int nE)
{
    int t = blockIdx.x * 256 + threadIdx.x;
    int e = t >> 5;
    if (e >= nE) return;
    int l = t & 31;
    int r = row[e];
    int c = col[e];
    float v = val[e];
    f32x4 x = *reinterpret_cast<const f32x4*>(X + (size_t)c * D + l * 4);
    float* o = out + (size_t)r * D + l * 4;
    unsafeAtomicAdd(o + 0, x[0] * v);
    unsafeAtomicAdd(o + 1, x[1] * v);
    unsafeAtomicAdd(o + 2, x[2] * v);
    unsafeAtomicAdd(o + 3, x[3] * v);
}

__global__ __launch_bounds__(256)
void gemm_relu_fb(const float* __restrict__ Xself, const float* __restrict__ Neigh,
                  const float* __restrict__ Wself, const float* __restrict__ Wneigh,
                  float* __restrict__ out, int nRows)
{
    const int tid  = threadIdx.x;
    const int wave = tid >> 6;
    const int lane = tid & 63;
    const int l15  = lane & 15;
    const int lhi  = lane >> 4;

    bf16x8 bfrag[2][8];
#pragma unroll
    for (int n = 0; n < 2; ++n) {
        int j = wave * 32 + n * 16 + l15;
#pragma unroll
        for (int kb = 0; kb < 8; ++kb) {
            int k = kb * 32 + lhi * 8;
            const float* src = (kb < 4) ? (Wself + j * D + k)
                                        : (Wneigh + j * D + (k - 128));
            f32x4 lo = *reinterpret_cast<const f32x4*>(src);
            f32x4 hi = *reinterpret_cast<const f32x4*>(src + 4);
            bfrag[n][kb] = pack8(lo, hi);
        }
    }

    int r0base = blockIdx.x * 128;
#pragma unroll 1
    for (int it = 0; it < 8; ++it) {
        int r0 = r0base + it * 16;
        if (r0 >= nRows) break;
        const float* xrow = Xself + (size_t)(r0 + l15) * D;
        const float* nrow = Neigh + (size_t)(r0 + l15) * D;
        bf16x8 afrag[8];
#pragma unroll
        for (int kb = 0; kb < 8; ++kb) {
            const float* src = (kb < 4) ? (xrow + kb * 32 + lhi * 8)
                                        : (nrow + (kb - 4) * 32 + lhi * 8);
            f32x4 lo = *reinterpret_cast<const f32x4*>(src);
            f32x4 hi = *reinterpret_cast<const f32x4*>(src + 4);
            afrag[kb] = pack8(lo, hi);
        }
        asm volatile("s_waitcnt vmcnt(0)" ::: "memory");
        __syncthreads();

        f32x4 acc0 = {0.f, 0.f, 0.f, 0.f};
        f32x4 acc1 = {0.f, 0.f, 0.f, 0.f};
#pragma unroll
        for (int kb = 0; kb < 8; ++kb) {
            acc0 = __builtin_amdgcn_mfma_f32_16x16x32_bf16(afrag[kb], bfrag[0][kb], acc0, 0, 0, 0);
            acc1 = __builtin_amdgcn_mfma_f32_16x16x32_bf16(afrag[kb], bfrag[1][kb], acc1, 0, 0, 0);
        }
#pragma unroll
        for (int i = 0; i < 4; ++i) {
            int rr = r0 + lhi * 4 + i;
            if (rr < nRows) {
                float v0 = acc0[i] > 0.f ? acc0[i] : 0.f;
                float v1 = acc1[i] > 0.f ? acc1[i] : 0.f;
                out[(size_t)rr * D + wave * 32 + l15]      = v0;
                out[(size_t)rr * D + wave * 32 + 16 + l15] = v1;
            }
        }
    }
}

// ---------------- launch ----------------

extern "C" void kernel_launch(void* const* d_in, const int* in_sizes, int n_in,
                              void* d_out, int out_size, void* d_ws, size_t ws_size,
                              hipStream_t stream)
{
    const float* Xg_self  = (const float*)d_in[0];
    const float* Xs_self  = (const float*)d_in[1];
    const float* Xs_for_g = (const float*)d_in[2];
    const float* Xg_for_s = (const float*)d_in[3];
    const int*   row_gs   = (const int*)d_in[4];
    const int*   col_gs   = (const int*)d_in[5];
    const float* val_gs   = (const float*)d_in[6];
    const int*   row_sg   = (const int*)d_in[7];
    const int*   col_sg   = (const int*)d_in[8];
    const float* val_sg   = (const float*)d_in[9];
    const float* Wg_self  = (const float*)d_in[10];
    const float* Wg_neigh = (const float*)d_in[11];
    const float* Ws_self  = (const float*)d_in[12];
    const float* Ws_neigh = (const float*)d_in[13];

    const int NG = in_sizes[0] / D;
    const int NS = in_sizes[1] / D;
    const int E1 = in_sizes[4];
    const int E2 = in_sizes[7];
    const int N  = NG + NS;
    const int Etot = E1 + E2;

    float* out_g = (float*)d_out;
    float* out_s = out_g + (size_t)NG * D;

    // ---- workspace layout ----
    size_t off = 0;
    auto alloc = [&](size_t bytes) -> size_t {
        off = (off + 255) & ~(size_t)255;
        size_t o = off;
        off += bytes;
        return o;
    };
    size_t x16g_o   = alloc(sizeof(short) * (size_t)NG * D);
    size_t x16s_o   = alloc(sizeof(short) * (size_t)NS * D);
    size_t wcat_o   = alloc(sizeof(short) * 2 * 128 * 256);
    size_t cnt_o    = alloc(sizeof(int) * N);
    size_t cursor_o = alloc(sizeof(int) * N);
    size_t pairs_o  = alloc(sizeof(int2) * (size_t)Etot);
    size_t blk_o    = alloc(sizeof(int) * 1024);
    size_t need_bytes = off;

    char* ws = (char*)d_ws;

    if (ws_size < need_bytes) {
        // ---- fallback: atomic scatter + in-place register GEMM ----
        hipMemsetAsync(d_out, 0, (size_t)out_size * sizeof(float), stream);
        {
            long long threads = (long long)E1 * 32;
            scatter_edges<<<(int)((threads + 255) / 256), 256, 0, stream>>>(
                Xs_for_g, row_gs, col_gs, val_gs, out_g, E1);
        }
        {
            long long threads = (long long)E2 * 32;
            scatter_edges<<<(int)((threads + 255) / 256), 256, 0, stream>>>(
                Xg_for_s, row_sg, col_sg, val_sg, out_s, E2);
        }
        gemm_relu_fb<<<(NG + 127) / 128, 256, 0, stream>>>(Xg_self, out_g, Wg_self, Wg_neigh, out_g, NG);
        gemm_relu_fb<<<(NS + 127) / 128, 256, 0, stream>>>(Xs_self, out_s, Ws_self, Ws_neigh, out_s, NS);
        return;
    }

    unsigned short* x16g = (unsigned short*)(ws + x16g_o);
    unsigned short* x16s = (unsigned short*)(ws + x16s_o);
    short* wcat  = (short*)(ws + wcat_o);
    int* cnt     = (int*)(ws + cnt_o);
    int* cursor  = (int*)(ws + cursor_o);
    int2* pairs  = (int2*)(ws + pairs_o);
    int* blk     = (int*)(ws + blk_o);

    const int n8a = NG * D / 8, n8b = NS * D / 8;

    hipMemsetAsync(cnt, 0, sizeof(int) * N, stream);

    {
        long long tot = (long long)n8a + n8b + 2 * 128 * 32 + Etot;
        prep_kernel<<<(int)((tot + 255) / 256), 256, 0, stream>>>(
            Xs_for_g, Xg_for_s, x16g, x16s,
            Wg_self, Wg_neigh, Ws_self, Ws_neigh, wcat,
            row_gs, E1, row_sg, NG, cnt, n8a, n8b, Etot);
    }

    int nb = (N + 1023) / 1024;   // 196 <= 256
    scan1_kernel<<<nb, 256, 0, stream>>>(cnt, cursor, blk, N);
    scan2_kernel<<<1, 256, 0, stream>>>(blk, nb);
    scan3_kernel<<<(N + 255) / 256, 256, 0, stream>>>(cursor, blk, N);
    fill2_kernel<<<(Etot + 255) / 256, 256, 0, stream>>>(
        row_gs, col_gs, val_gs, E1, row_sg, col_sg, val_sg, NG, cursor, pairs, Etot);

    int blocks0 = (NG + 31) / 32, blocks1 = (NS + 31) / 32;
    fused_kernel<<<blocks0 + blocks1, 512, 0, stream>>>(
        x16g, x16s,
        Xg_self, out_g, NG,
        Xs_self, out_s, NS,
        cnt, cursor, pairs, wcat);
}